// Round 10
// baseline (87.124 us; speedup 1.0000x reference)
//
#include <hip/hip_runtime.h>

#define CH   128
#define KS   7
#define R    49
#define HH   56
#define NPOS 3136
#define BS   8
#define XSTR 401408
#define XTOT (BS*XSTR)

typedef short short8 __attribute__((ext_vector_type(8)));
typedef float f32x4  __attribute__((ext_vector_type(4)));
typedef unsigned int u32;
typedef u32 u32x4 __attribute__((ext_vector_type(4)));

__device__ __forceinline__ short f2bf(float f) {            // RNE fp32->bf16
    unsigned u = __float_as_uint(f);
    u += 0x7fffu + ((u >> 16) & 1u);
    return (short)(u >> 16);
}
__device__ __forceinline__ float bf2f(short s) {
    return __uint_as_float(((unsigned)(unsigned short)s) << 16);
}

#define HSTR 136            // hid LDS row stride (bf16 elems)
#define PSTR 132            // P LDS row stride (fp32) - mono fallback only
#define NWIN 3140           // win dwords per batch buffer (785 u32x4 chunks)

// ---------- prep: W2 (fp32 [m][ch]) -> W2^T hi/lo bf16 ([ch][m]) ----------
__global__ __launch_bounds__(256) void poatt_prep(
    const float* __restrict__ W2, short* __restrict__ wsH, short* __restrict__ wsL)
{
    int t = blockIdx.x * 256 + threadIdx.x;
    int k = t >> 7, ch = t & 127;
    float w = W2[k * CH + ch];
    short hi = f2bf(w);
    wsH[ch * CH + k] = hi;
    wsL[ch * CH + k] = f2bf(w - bf2f(hi));
}

// ---------- cvt: x fp32 -> bf16 pairs ----------
__global__ __launch_bounds__(256) void poatt_cvt(
    const float* __restrict__ x, u32* __restrict__ x2)
{
    int t = blockIdx.x * 256 + threadIdx.x;      // 1568 blocks
    const float4* xv = reinterpret_cast<const float4*>(x);
    float4 a = xv[2 * t], b = xv[2 * t + 1];
    u32x4 o;
    o[0] = (u32)(unsigned short)f2bf(a.x) | ((u32)(unsigned short)f2bf(a.y) << 16);
    o[1] = (u32)(unsigned short)f2bf(a.z) | ((u32)(unsigned short)f2bf(a.w) << 16);
    o[2] = (u32)(unsigned short)f2bf(b.x) | ((u32)(unsigned short)f2bf(b.y) << 16);
    o[3] = (u32)(unsigned short)f2bf(b.z) | ((u32)(unsigned short)f2bf(b.w) << 16);
    reinterpret_cast<u32x4*>(x2)[t] = o;
}

// ---------- fused: weights (MFMA + in-reg softmax) + batch-pair apply ----------
__global__ __launch_bounds__(256, 4) void poatt_fused(
    const u32* __restrict__ x2,
    const float* __restrict__ W1, const float* __restrict__ b1,
    const short* __restrict__ wsH, const short* __restrict__ wsL,
    float* __restrict__ trb)         // (b,pos,ch)
{
    __shared__ float rel_s[R][2];
    __shared__ __align__(16) char smemA[64 * HSTR * 2];   // 17408 B: hid, then win0
    __shared__ __align__(16) char smemB[25 * CH * 4];     // 12800 B: wpack, then win1
    short* hid_s = (short*)smemA;
    u32*   wpack = (u32*)smemB;
    u32*   win0  = (u32*)smemA;                           // 12560 B used
    u32*   win1  = (u32*)smemB;                           // 12560 B used

    const int pos = blockIdx.x;                           // natural: XCD = s mod 8
    const int tid = threadIdx.x;
    const int ch  = tid & (CH - 1);
    const int g   = tid >> 7;

    const int q  = pos >> 6;
    const int s  = pos & 63;
    const int ii = q / KS;
    const int jj = q % KS;

    // ---------- phase 0: rel ----------
    if (tid < 2 * R) {
        const int e  = (tid >= R) ? 1 : 0;
        const int rr = tid - e * R;
        int F  = (pos * 2 + e) * R + rr;
        int ep = F & 1;
        int t  = F >> 1;
        int jp = t % HH; t /= HH;
        int a  = t % HH; t /= HH;
        int jc = t % KS;
        int ic = t / KS;
        int row = jp + ic - 3;
        int col = ep + jc - 3;
        float v = 0.0f;
        if (row >= 0 && row < HH && (col == 0 || col == 1)) {
            int f    = a * (HH * 2) + row * 2 + col;
            int cidx = f / NPOS;
            int p    = f - cidx * NPOS;
            int u    = (cidx == 0) ? (p / HH) : (p % HH);
            v = -3.0f + 6.0f * (float)u * (1.0f / 55.0f);
        }
        const float c0 = -3.0f + 6.0f * (float)(pos / HH) * (1.0f / 55.0f);
        const float c1 = -3.0f + 6.0f * (float)(pos % HH) * (1.0f / 55.0f);
        rel_s[rr][e] = v - ((e == 0) ? c0 : c1);
    }
    __syncthreads();

    // ---------- phase 1: hid = relu(rel@W1+b1) -> bf16 LDS ----------
    {
        const float w10 = W1[ch];
        const float w11 = W1[CH + ch];
        const float bb  = b1[ch];
        for (int rr = g; rr < R; rr += 2) {
            float h = fmaf(rel_s[rr][0], w10, fmaf(rel_s[rr][1], w11, bb));
            hid_s[rr * HSTR + ch] = f2bf(fmaxf(h, 0.0f));
        }
        for (int t = tid; t < 15 * HSTR; t += 256) hid_s[R * HSTR + t] = 0;
    }
    __syncthreads();

    // ---------- window geometry ----------
    const int winbase = s * (R * CH) + (ii - 3) * CH + (jj - 3);
    const int hw  = winbase >> 1;                 // floor (arith shift)
    const int m3  = hw & 3;
    const int cw0 = (hw - m3) >> 2;               // u32x4 chunk base (batch plane)
    const u32x4* x2v = reinterpret_cast<const u32x4*>(x2);
    const unsigned short* x2s = reinterpret_cast<const unsigned short*>(x2);

    u32x4 vA[4], vB[4];
    auto ldbuf = [&](int b, u32x4* v) {
        const bool safe = (b > 0 || winbase >= 8) && (b < BS - 1 || winbase + 6280 <= XSTR);
        const int cb = b * (XSTR >> 3) + cw0;
        if (safe) {
            v[0] = x2v[cb + tid];
            v[1] = x2v[cb + tid + 256];
            v[2] = x2v[cb + tid + 512];
            if (tid < 17) v[3] = x2v[cb + tid + 768];
        } else {
            #pragma unroll
            for (int j = 0; j < 4; ++j) {
                if (j < 3 || tid < 17) {
                    int gc = cb + tid + 256 * j;
                    u32x4 o;
                    #pragma unroll
                    for (int kk = 0; kk < 4; ++kk) {
                        int e0 = 8 * gc + 2 * kk;
                        int a0 = e0;     a0 = a0 < 0 ? 0 : (a0 >= XTOT ? XTOT - 1 : a0);
                        int a1 = e0 + 1; a1 = a1 < 0 ? 0 : (a1 >= XTOT ? XTOT - 1 : a1);
                        o[kk] = (u32)x2s[a0] | ((u32)x2s[a1] << 16);  // masked (w=0)
                    }
                    v[j] = o;
                }
            }
        }
    };
    auto stbuf = [&](const u32x4* v, u32* wb) {   // linear layout, b128 writes
        *reinterpret_cast<u32x4*>(&wb[4 * tid])         = v[0];
        *reinterpret_cast<u32x4*>(&wb[4 * (tid + 256)]) = v[1];
        *reinterpret_cast<u32x4*>(&wb[4 * (tid + 512)]) = v[2];
        if (tid < 17)
            *reinterpret_cast<u32x4*>(&wb[4 * (tid + 768)]) = v[3];
    };

    ldbuf(0, vA);   // batch-0 loads in flight across the MFMA phase

    // ---------- phase 2: P columns [32w,32w+32) via 2-term MFMA ----------
    const int wv_ = tid >> 6;
    const int l   = tid & 63;
    const int lr  = l & 15;
    const int kg  = l >> 4;

    f32x4 acc[4][2];
    #pragma unroll
    for (int mt = 0; mt < 4; ++mt) { acc[mt][0] = (f32x4)0.0f; acc[mt][1] = (f32x4)0.0f; }

    #pragma unroll
    for (int np = 0; np < 2; ++np) {
        const int bcol = 32 * wv_ + 16 * np + lr;
        short8 bH[4], bL[4];
        #pragma unroll
        for (int kk = 0; kk < 4; ++kk) {
            bH[kk] = *reinterpret_cast<const short8*>(wsH + bcol * CH + kk * 32 + kg * 8);
            bL[kk] = *reinterpret_cast<const short8*>(wsL + bcol * CH + kk * 32 + kg * 8);
        }
        #pragma unroll
        for (int mt = 0; mt < 4; ++mt) {
            #pragma unroll
            for (int kk = 0; kk < 4; ++kk) {
                short8 a = *reinterpret_cast<const short8*>(
                    &hid_s[(16 * mt + lr) * HSTR + kk * 32 + kg * 8]);
                acc[mt][np] = __builtin_amdgcn_mfma_f32_16x16x32_bf16(a, bH[kk], acc[mt][np], 0, 0, 0);
                acc[mt][np] = __builtin_amdgcn_mfma_f32_16x16x32_bf16(a, bL[kk], acc[mt][np], 0, 0, 0);
            }
        }
    }

    // ---------- phase 3: in-reg softmax + mask -> wpack ----------
    {
        const int wb0 = s * (R * CH);
        float wv[4][4];
        #pragma unroll
        for (int np = 0; np < 2; ++np) {
            const int chh = 32 * wv_ + 16 * np + lr;

            float mx = -1e30f;
            #pragma unroll
            for (int mt = 0; mt < 4; ++mt)
                #pragma unroll
                for (int r = 0; r < 4; ++r) {
                    int rr = 16 * mt + 4 * kg + r;
                    if (rr < R) mx = fmaxf(mx, acc[mt][np][r]);
                }
            mx = fmaxf(mx, __shfl_xor(mx, 16));
            mx = fmaxf(mx, __shfl_xor(mx, 32));

            float sm = 0.0f;
            #pragma unroll
            for (int mt = 0; mt < 4; ++mt)
                #pragma unroll
                for (int r = 0; r < 4; ++r) {
                    int rr = 16 * mt + 4 * kg + r;
                    float e = (rr < R) ? __expf(acc[mt][np][r] - mx) : 0.0f;
                    wv[mt][r] = e;
                    sm += e;
                }
            sm += __shfl_xor(sm, 16);
            sm += __shfl_xor(sm, 32);
            const float inv = 1.0f / sm;

            #pragma unroll
            for (int mt = 0; mt < 4; ++mt)
                #pragma unroll
                for (int r = 0; r < 4; ++r) {
                    int rr = 16 * mt + 4 * kg + r;
                    if (rr < R) {
                        int rem = wb0 + chh * R + rr;
                        int e2  = rem & (CH - 1);
                        int j2  = (rem >> 7) % HH;
                        int row = j2 + ii - 3;
                        int col = e2 + jj - 3;
                        bool valid = (row >= 0) && (row < HH) && (col >= 0) && (col < CH);
                        wv[mt][r] = valid ? wv[mt][r] * inv : 0.0f;
                    }
                }

            #pragma unroll
            for (int mt = 0; mt < 4; ++mt)
                #pragma unroll
                for (int jp = 0; jp < 2; ++jp) {
                    int j = 8 * mt + 2 * kg + jp;
                    if (j <= 24) {
                        u32 pk = (u32)(unsigned short)f2bf(wv[mt][2 * jp])
                               | ((u32)(unsigned short)f2bf(wv[mt][2 * jp + 1]) << 16);
                        wpack[j * CH + chh] = pk;
                    }
                }
        }
    }
    __syncthreads();          // B1: hid dead, wpack visible

    ldbuf(1, vB);             // issue batch-1 loads (hidden under qw/stA/B2)

    // ---------- per-thread weights: parity-aligned packed pairs -> qlo/qhi ----------
    const int p_ = (winbase + 49 * ch) & 1;
    float qlo[25], qhi[25];
    {
        u32 wr2[25];
        #pragma unroll
        for (int i = 0; i < 25; ++i) wr2[i] = wpack[i * CH + ch];
        #pragma unroll
        for (int i = 0; i < 25; ++i) {
            u32 qp = p_ ? ((wr2[i] << 16) | (i ? (wr2[i - 1] >> 16) : 0u)) : wr2[i];
            qlo[i] = __uint_as_float(qp << 16);
            qhi[i] = __uint_as_float(qp & 0xffff0000u);
        }
    }

    stbuf(vA, win0);          // overlays hid (dead after B1)
    __syncthreads();          // B2: wpack reads done, win0 visible
    stbuf(vB, win1);          // overlays wpack (dead after B2)
    ldbuf(2, vA);
    ldbuf(3, vB);
    __syncthreads();          // B3: win1 visible

    // ---------- batch-pair loop: g=0 -> batch 2k (win0), g=1 -> 2k+1 (win1) ----------
    const int base_l = ((winbase + 49 * ch) >> 1) - (hw - m3);
    const u32* wb = g ? win1 : win0;

    for (int k = 0; k < 4; ++k) {
        float acc2 = 0.0f;
        #pragma unroll
        for (int d = 0; d < 25; ++d) {
            u32 wd = wb[base_l + d];
            acc2 = fmaf(__uint_as_float(wd << 16),          qlo[d], acc2);
            acc2 = fmaf(__uint_as_float(wd & 0xffff0000u),  qhi[d], acc2);
        }
        trb[((size_t)(2 * k + g) * NPOS + pos) * CH + ch] = acc2;

        if (k < 3) {
            __syncthreads();                     // win reads done
            stbuf(vA, win0);                     // batch 2k+2
            stbuf(vB, win1);                     // batch 2k+3
            if (k < 2) { ldbuf(2 * k + 4, vA); ldbuf(2 * k + 5, vB); }
            __syncthreads();                     // staged visible
        }
    }
}

// ---------- transpose (b,pos,ch) -> (b,ch,pos) ----------
__global__ __launch_bounds__(256) void poatt_tr(
    const float* __restrict__ ws, float* __restrict__ out)
{
    __shared__ float t[64 * 129];
    const int blk = blockIdx.x;
    const int b   = blk / 49;
    const int p0  = (blk % 49) * 64;
    const int tid = threadIdx.x;

    const int chR = tid & 127, pR = tid >> 7;
    #pragma unroll
    for (int r = 0; r < 32; ++r) {
        int pl = pR + 2 * r;
        t[pl * 129 + chR] = ws[((size_t)b * NPOS + p0 + pl) * CH + chR];
    }
    __syncthreads();
    const int pW = tid & 63, chW0 = tid >> 6;
    #pragma unroll
    for (int c = 0; c < 32; ++c) {
        int chl = chW0 + 4 * c;
        out[((size_t)b * CH + chl) * NPOS + p0 + pW] = t[pW * 129 + chl];
    }
}

// ================= fallback: monolithic kernel (round-4 proven) =================
template<bool WS_W2, bool USE_WS>
__global__ __launch_bounds__(256, 4) void poatt_mono(
    const float* __restrict__ x,
    const float* __restrict__ W1, const float* __restrict__ b1,
    const float* __restrict__ W2,
    const short* __restrict__ wsH, const short* __restrict__ wsL,
    float* __restrict__ dst)
{
    __shared__ float rel_s[R][2];
    __shared__ __align__(16) char smem[2 * 64 * HSTR * 2];
    short* hidH = (short*)smem;
    short* hidL = hidH + 64 * HSTR;
    float* Pbuf = (float*)smem;

    const int pos = blockIdx.x;
    const int tid = threadIdx.x;
    const int ch  = tid & (CH - 1);
    const int g   = tid >> 7;

    const int q  = pos >> 6;
    const int ii = q / KS;
    const int jj = q % KS;

    if (tid < 2 * R) {
        const int e  = (tid >= R) ? 1 : 0;
        const int rr = tid - e * R;
        int F  = (pos * 2 + e) * R + rr;
        int ep = F & 1;
        int t  = F >> 1;
        int jp = t % HH; t /= HH;
        int a  = t % HH; t /= HH;
        int jc = t % KS;
        int ic = t / KS;
        int row = jp + ic - 3;
        int col = ep + jc - 3;
        float v = 0.0f;
        if (row >= 0 && row < HH && (col == 0 || col == 1)) {
            int f    = a * (HH * 2) + row * 2 + col;
            int cidx = f / NPOS;
            int p    = f - cidx * NPOS;
            int u    = (cidx == 0) ? (p / HH) : (p % HH);
            v = -3.0f + 6.0f * (float)u * (1.0f / 55.0f);
        }
        const float c0 = -3.0f + 6.0f * (float)(pos / HH) * (1.0f / 55.0f);
        const float c1 = -3.0f + 6.0f * (float)(pos % HH) * (1.0f / 55.0f);
        rel_s[rr][e] = v - ((e == 0) ? c0 : c1);
    }
    __syncthreads();

    {
        const float w10 = W1[ch];
        const float w11 = W1[CH + ch];
        const float bb  = b1[ch];
        for (int rr = g; rr < R; rr += 2) {
            float h = fmaf(rel_s[rr][0], w10, fmaf(rel_s[rr][1], w11, bb));
            h = fmaxf(h, 0.0f);
            short hi = f2bf(h);
            hidH[rr * HSTR + ch] = hi;
            hidL[rr * HSTR + ch] = f2bf(h - bf2f(hi));
        }
        for (int t = tid; t < 15 * HSTR; t += 256) {
            hidH[R * HSTR + t] = 0;
            hidL[R * HSTR + t] = 0;
        }
    }
    __syncthreads();

    {
        const int w  = tid >> 6;
        const int l  = tid & 63;
        const int lr = l & 15;
        const int kg = l >> 4;

        short8 aH[4], aL[4];
        const int abase = (16 * w + lr) * HSTR + kg * 8;
        #pragma unroll
        for (int kk = 0; kk < 4; ++kk) {
            aH[kk] = *reinterpret_cast<const short8*>(&hidH[abase + kk * 32]);
            aL[kk] = *reinterpret_cast<const short8*>(&hidL[abase + kk * 32]);
        }

        f32x4 acc[8];
        #pragma unroll
        for (int n = 0; n < 8; ++n) acc[n] = (f32x4)0.0f;

        #pragma unroll
        for (int n = 0; n < 8; ++n) {
            const int bcol = 16 * n + lr;
            #pragma unroll
            for (int kk = 0; kk < 4; ++kk) {
                short8 bH, bL;
                if (WS_W2) {
                    bH = *reinterpret_cast<const short8*>(wsH + bcol * CH + kk * 32 + kg * 8);
                    bL = *reinterpret_cast<const short8*>(wsL + bcol * CH + kk * 32 + kg * 8);
                } else {
                    #pragma unroll
                    for (int j = 0; j < 8; ++j) {
                        float ww = ((const float*)W2)[(kk * 32 + kg * 8 + j) * CH + bcol];
                        short hi = f2bf(ww);
                        bH[j] = hi;
                        bL[j] = f2bf(ww - bf2f(hi));
                    }
                }
                acc[n] = __builtin_amdgcn_mfma_f32_16x16x32_bf16(aL[kk], bH, acc[n], 0, 0, 0);
                acc[n] = __builtin_amdgcn_mfma_f32_16x16x32_bf16(aH[kk], bL, acc[n], 0, 0, 0);
                acc[n] = __builtin_amdgcn_mfma_f32_16x16x32_bf16(aH[kk], bH, acc[n], 0, 0, 0);
            }
        }
        __syncthreads();

        #pragma unroll
        for (int n = 0; n < 8; ++n) {
            #pragma unroll
            for (int r = 0; r < 4; ++r) {
                int rr = 16 * w + kg * 4 + r;
                if (rr < R) Pbuf[rr * PSTR + 16 * n + lr] = acc[n][r];
            }
        }
    }
    __syncthreads();

    if (tid < CH) {
        float p[R];
        #pragma unroll
        for (int rr = 0; rr < R; ++rr) p[rr] = Pbuf[rr * PSTR + tid];
        float mx = p[0];
        #pragma unroll
        for (int rr = 1; rr < R; ++rr) mx = fmaxf(mx, p[rr]);
        float s = 0.0f;
        #pragma unroll
        for (int rr = 0; rr < R; ++rr) { p[rr] = __expf(p[rr] - mx); s += p[rr]; }
        const float inv = 1.0f / s;
        const int wb0 = (pos & 63) * (R * CH);
        #pragma unroll
        for (int rr = 0; rr < R; ++rr) {
            int rem = wb0 + tid * R + rr;
            int e2  = rem & (CH - 1);
            int j2  = (rem >> 7) % HH;
            int row = j2 + ii - 3;
            int col = e2 + jj - 3;
            bool valid = (row >= 0) && (row < HH) && (col >= 0) && (col < CH);
            Pbuf[rr * PSTR + tid] = valid ? p[rr] * inv : 0.0f;
        }
    }
    __syncthreads();

    float p[R];
    #pragma unroll
    for (int rr = 0; rr < R; ++rr) p[rr] = Pbuf[rr * PSTR + ch];

    const int winbase = (pos & 63) * (R * CH) + (ii - 3) * CH + (jj - 3);
    const int base_t  = winbase + ch * R;

    #pragma unroll
    for (int bi = 0; bi < 4; ++bi) {
        const int b  = g * 4 + bi;
        const int ab = b * XSTR + base_t;
        const bool safe = (b > 0 || winbase >= 0) && (b < BS - 1 || winbase + R * CH <= XSTR);
        float acc = 0.0f;
        if (safe) {
            #pragma unroll
            for (int rr = 0; rr < R; ++rr) acc = fmaf(p[rr], x[ab + rr], acc);
        } else {
            #pragma unroll
            for (int rr = 0; rr < R; ++rr) {
                int a2 = ab + rr;
                a2 = a2 < 0 ? 0 : (a2 >= XTOT ? XTOT - 1 : a2);
                acc = fmaf(p[rr], x[a2], acc);
            }
        }
        if (USE_WS) dst[((size_t)b * NPOS + pos) * CH + ch] = acc;
        else        dst[((size_t)b * CH + ch) * NPOS + pos] = acc;
    }
}

extern "C" void kernel_launch(void* const* d_in, const int* in_sizes, int n_in,
                              void* d_out, int out_size, void* d_ws, size_t ws_size,
                              hipStream_t stream) {
    (void)in_sizes; (void)n_in; (void)out_size;
    const float* x  = (const float*)d_in[0];
    const float* W1 = (const float*)d_in[1];
    const float* b1 = (const float*)d_in[2];
    const float* W2 = (const float*)d_in[3];
    float* out = (float*)d_out;

    // ws layout: [W2T hi/lo 64KB][x2 bf16 6.125MB][trb 12.25MB]
    const size_t W2T_BYTES = 2u * CH * CH * sizeof(short);            //    65536
    const size_t X2_BYTES  = (size_t)XTOT * 2;                        //  6422528
    const size_t TRB_BYTES = (size_t)BS * NPOS * CH * sizeof(float);  // 12845056
    const size_t FULL = W2T_BYTES + X2_BYTES + TRB_BYTES;             // 19333120

    short* wsH = (short*)d_ws;
    short* wsL = wsH + CH * CH;

    if (ws_size >= FULL) {
        u32*   x2  = (u32*)((char*)d_ws + W2T_BYTES);
        float* trb = (float*)((char*)d_ws + W2T_BYTES + X2_BYTES);

        poatt_prep<<<dim3(64), dim3(256), 0, stream>>>(W2, wsH, wsL);
        poatt_cvt<<<dim3(XTOT / (256 * 8)), dim3(256), 0, stream>>>(x, x2);
        poatt_fused<<<dim3(NPOS), dim3(256), 0, stream>>>(x2, W1, b1, wsH, wsL, trb);
        poatt_tr<<<dim3(BS * 49), dim3(256), 0, stream>>>(trb, out);
    } else if (ws_size >= W2T_BYTES + TRB_BYTES) {
        float* trb = (float*)((char*)d_ws + W2T_BYTES);
        poatt_prep<<<dim3(64), dim3(256), 0, stream>>>(W2, wsH, wsL);
        poatt_mono<true, true><<<dim3(NPOS), dim3(256), 0, stream>>>(
            x, W1, b1, W2, wsH, wsL, trb);
        poatt_tr<<<dim3(BS * 49), dim3(256), 0, stream>>>(trb, out);
    } else if (ws_size >= W2T_BYTES) {
        poatt_prep<<<dim3(64), dim3(256), 0, stream>>>(W2, wsH, wsL);
        poatt_mono<true, false><<<dim3(NPOS), dim3(256), 0, stream>>>(
            x, W1, b1, W2, wsH, wsL, out);
    } else {
        poatt_mono<false, false><<<dim3(NPOS), dim3(256), 0, stream>>>(
            x, W1, b1, W2, nullptr, nullptr, out);
    }
}

// Round 11
// 75.530 us; speedup vs baseline: 1.1535x; 1.1535x over previous
//
#include <hip/hip_runtime.h>

#define CH   128
#define KS   7
#define R    49
#define HH   56
#define NPOS 3136
#define BS   8
#define XSTR 401408
#define XTOT (BS*XSTR)

typedef short short8 __attribute__((ext_vector_type(8)));
typedef float f32x4  __attribute__((ext_vector_type(4)));
typedef unsigned int u32;
typedef unsigned long long u64;
typedef u32 u32x4 __attribute__((ext_vector_type(4)));

__device__ __forceinline__ short f2bf(float f) {            // RNE fp32->bf16
    unsigned u = __float_as_uint(f);
    u += 0x7fffu + ((u >> 16) & 1u);
    return (short)(u >> 16);
}
__device__ __forceinline__ float bf2f(short s) {
    return __uint_as_float(((unsigned)(unsigned short)s) << 16);
}
__device__ __forceinline__ float bf2f_u(u32 lo16) {
    return __uint_as_float(lo16 << 16);
}
__device__ __forceinline__ u64 bitrange(int a, int b) {     // bits [a,b) clamped to [0,49]
    a = a < 0 ? 0 : (a > 49 ? 49 : a);
    b = b < 0 ? 0 : (b > 49 ? 49 : b);
    if (b <= a) return 0ull;
    return (1ull << b) - (1ull << a);
}

#define HSTR 136            // hid LDS row stride (bf16 elems)
#define PSTR 132            // P LDS row stride (fp32) - mono fallback only
#define NWIN 3140           // win dwords (785 u32x4 chunks)

// ---------- prep (fallback path only) ----------
__global__ __launch_bounds__(256) void poatt_prep(
    const float* __restrict__ W2, short* __restrict__ wsH, short* __restrict__ wsL)
{
    int t = blockIdx.x * 256 + threadIdx.x;
    int k = t >> 7, ch = t & 127;
    float w = W2[k * CH + ch];
    short hi = f2bf(w);
    wsH[ch * CH + k] = hi;
    wsL[ch * CH + k] = f2bf(w - bf2f(hi));
}

// ---------- combined: cvt x->bf16 pairs + W2 prep (first 64 blocks) ----------
__global__ __launch_bounds__(256) void poatt_pc(
    const float* __restrict__ x, const float* __restrict__ W2,
    u32* __restrict__ x2, short* __restrict__ wsH, short* __restrict__ wsL)
{
    int t = blockIdx.x * 256 + threadIdx.x;      // grid 1568
    const float4* xv = reinterpret_cast<const float4*>(x);
    float4 a = xv[2 * t], b = xv[2 * t + 1];
    u32x4 o;
    o[0] = (u32)(unsigned short)f2bf(a.x) | ((u32)(unsigned short)f2bf(a.y) << 16);
    o[1] = (u32)(unsigned short)f2bf(a.z) | ((u32)(unsigned short)f2bf(a.w) << 16);
    o[2] = (u32)(unsigned short)f2bf(b.x) | ((u32)(unsigned short)f2bf(b.y) << 16);
    o[3] = (u32)(unsigned short)f2bf(b.z) | ((u32)(unsigned short)f2bf(b.w) << 16);
    reinterpret_cast<u32x4*>(x2)[t] = o;

    if (t < CH * CH) {
        int k = t >> 7, ch = t & 127;
        float w = W2[k * CH + ch];
        short hi = f2bf(w);
        wsH[ch * CH + k] = hi;
        wsL[ch * CH + k] = f2bf(w - bf2f(hi));
    }
}

// ---------- fused: weights (MFMA + in-reg softmax) + 8-batch apply ----------
__global__ __launch_bounds__(256, 4) void poatt_fused(
    const u32* __restrict__ x2,
    const float* __restrict__ W1, const float* __restrict__ b1,
    const short* __restrict__ wsH, const short* __restrict__ wsL,
    float* __restrict__ trb)         // (b,pos,ch)
{
    __shared__ float rel_s[R][2];
    __shared__ float part_s[CH];
    __shared__ u32 wpack[25 * CH];                    // 12800 B: weights [j][ch]
    __shared__ __align__(16) char smem[64 * HSTR * 2];// 17408 B: hid, then win (linear)
    short* hid_s = (short*)smem;
    u32*   win   = (u32*)smem;                        // NWIN dwords used (12560 B)

    const int pos = blockIdx.x;                       // natural: XCD = s mod 8
    const int tid = threadIdx.x;
    const int ch  = tid & (CH - 1);
    const int g   = tid >> 7;

    const int q  = pos >> 6;
    const int s  = pos & 63;
    const int ii = q / KS;
    const int jj = q % KS;

    // ---------- phase 0: rel ----------
    if (tid < 2 * R) {
        const int e  = (tid >= R) ? 1 : 0;
        const int rr = tid - e * R;
        int F  = (pos * 2 + e) * R + rr;
        int ep = F & 1;
        int t  = F >> 1;
        int jp = t % HH; t /= HH;
        int a  = t % HH; t /= HH;
        int jc = t % KS;
        int ic = t / KS;
        int row = jp + ic - 3;
        int col = ep + jc - 3;
        float v = 0.0f;
        if (row >= 0 && row < HH && (col == 0 || col == 1)) {
            int f    = a * (HH * 2) + row * 2 + col;
            int cidx = f / NPOS;
            int p    = f - cidx * NPOS;
            int u    = (cidx == 0) ? (p / HH) : (p % HH);
            v = -3.0f + 6.0f * (float)u * (1.0f / 55.0f);
        }
        const float c0 = -3.0f + 6.0f * (float)(pos / HH) * (1.0f / 55.0f);
        const float c1 = -3.0f + 6.0f * (float)(pos % HH) * (1.0f / 55.0f);
        rel_s[rr][e] = v - ((e == 0) ? c0 : c1);
    }
    __syncthreads();

    // ---------- phase 1: hid = relu(rel@W1+b1) -> bf16 LDS ----------
    {
        const float w10 = W1[ch];
        const float w11 = W1[CH + ch];
        const float bb  = b1[ch];
        for (int rr = g; rr < R; rr += 2) {
            float h = fmaf(rel_s[rr][0], w10, fmaf(rel_s[rr][1], w11, bb));
            hid_s[rr * HSTR + ch] = f2bf(fmaxf(h, 0.0f));
        }
        for (int t = tid; t < 15 * HSTR; t += 256) hid_s[R * HSTR + t] = 0;
    }
    __syncthreads();

    // ---------- window geometry ----------
    const int winbase = s * (R * CH) + (ii - 3) * CH + (jj - 3);
    const int m2v = winbase & 1;
    const int hw  = winbase >> 1;
    const int m3  = hw & 3;
    const int cw0 = (hw - m3) >> 2;               // u32x4 chunk base (batch plane)
    const u32x4* x2v = reinterpret_cast<const u32x4*>(x2);
    const unsigned short* x2s = reinterpret_cast<const unsigned short*>(x2);

    u32x4 v[4];
    auto ld = [&](int b) {
        const int cb = b * (XSTR >> 3) + cw0;
        const bool safe = (b > 0 || winbase >= 8) && (b < BS - 1 || winbase + 6280 <= XSTR);
        if (safe) {
            v[0] = x2v[cb + tid];
            v[1] = x2v[cb + tid + 256];
            v[2] = x2v[cb + tid + 512];
            if (tid < 17) v[3] = x2v[cb + tid + 768];
        } else {
            #pragma unroll
            for (int j = 0; j < 4; ++j) {
                if (j < 3 || tid < 17) {
                    int gc = cb + tid + 256 * j;
                    u32x4 o;
                    #pragma unroll
                    for (int kk = 0; kk < 4; ++kk) {
                        int e0 = 8 * gc + 2 * kk;
                        int a0 = e0;     a0 = a0 < 0 ? 0 : (a0 >= XTOT ? XTOT - 1 : a0);
                        int a1 = e0 + 1; a1 = a1 < 0 ? 0 : (a1 >= XTOT ? XTOT - 1 : a1);
                        o[kk] = (u32)x2s[a0] | ((u32)x2s[a1] << 16);  // masked (w=0)
                    }
                    v[j] = o;
                }
            }
        }
    };
    auto st = [&]() {   // linear layout, 4x ds_write_b128, conflict-free
        *reinterpret_cast<u32x4*>(&win[4 * tid])         = v[0];
        *reinterpret_cast<u32x4*>(&win[4 * (tid + 256)]) = v[1];
        *reinterpret_cast<u32x4*>(&win[4 * (tid + 512)]) = v[2];
        if (tid < 17)
            *reinterpret_cast<u32x4*>(&win[4 * (tid + 768)]) = v[3];
    };

    ld(0);   // batch-0 loads in flight across the MFMA phase

    // ---------- phase 2: P columns [32w,32w+32) via 2-term MFMA ----------
    const int wv_ = tid >> 6;
    const int l   = tid & 63;
    const int lr  = l & 15;
    const int kg  = l >> 4;

    f32x4 acc[4][2];
    #pragma unroll
    for (int mt = 0; mt < 4; ++mt) { acc[mt][0] = (f32x4)0.0f; acc[mt][1] = (f32x4)0.0f; }

    #pragma unroll
    for (int np = 0; np < 2; ++np) {
        const int bcol = 32 * wv_ + 16 * np + lr;
        short8 bH[4], bL[4];
        #pragma unroll
        for (int kk = 0; kk < 4; ++kk) {
            bH[kk] = *reinterpret_cast<const short8*>(wsH + bcol * CH + kk * 32 + kg * 8);
            bL[kk] = *reinterpret_cast<const short8*>(wsL + bcol * CH + kk * 32 + kg * 8);
        }
        #pragma unroll
        for (int mt = 0; mt < 4; ++mt) {
            #pragma unroll
            for (int kk = 0; kk < 4; ++kk) {
                short8 a = *reinterpret_cast<const short8*>(
                    &hid_s[(16 * mt + lr) * HSTR + kk * 32 + kg * 8]);
                acc[mt][np] = __builtin_amdgcn_mfma_f32_16x16x32_bf16(a, bH[kk], acc[mt][np], 0, 0, 0);
                acc[mt][np] = __builtin_amdgcn_mfma_f32_16x16x32_bf16(a, bL[kk], acc[mt][np], 0, 0, 0);
            }
        }
    }

    // ---------- phase 3: in-reg softmax + interval-bitmask mask -> wpack ----------
    {
        float wv[4][4];
        #pragma unroll
        for (int np = 0; np < 2; ++np) {
            const int chh = 32 * wv_ + 16 * np + lr;

            float mx = -1e30f;
            #pragma unroll
            for (int mt = 0; mt < 4; ++mt)
                #pragma unroll
                for (int r = 0; r < 4; ++r) {
                    int rr = 16 * mt + 4 * kg + r;
                    if (rr < R) mx = fmaxf(mx, acc[mt][np][r]);
                }
            mx = fmaxf(mx, __shfl_xor(mx, 16));
            mx = fmaxf(mx, __shfl_xor(mx, 32));

            float sm = 0.0f;
            #pragma unroll
            for (int mt = 0; mt < 4; ++mt)
                #pragma unroll
                for (int r = 0; r < 4; ++r) {
                    int rr = 16 * mt + 4 * kg + r;
                    float e = (rr < R) ? __expf(acc[mt][np][r] - mx) : 0.0f;
                    wv[mt][r] = e;
                    sm += e;
                }
            sm += __shfl_xor(sm, 16);
            sm += __shfl_xor(sm, 32);
            const float inv = 1.0f / sm;

            // validity bitmask over rr in [0,49):
            // rem = base + rr; e2 = rem & 127; j2 = (rem>>7) % 56
            // col ok: 3-jj <= e2 <= 130-jj ; row ok: 3-ii <= j2 <= 58-ii
            const int base = s * (R * CH) + chh * R;
            const int e2_0 = base & 127;
            const int jb   = base >> 7;
            const int j2_0 = jb % HH;
            const int rw   = 128 - e2_0;          // e2-wrap point (>=1)
            int j2p = j2_0 + 1; if (j2p == HH) j2p = 0;
            const bool rok1 = (j2_0 >= 3 - ii) && (j2_0 < 59 - ii);
            const bool rok2 = (j2p  >= 3 - ii) && (j2p  < 59 - ii);
            const int c1 = (3 - jj) - e2_0;       // seg1 col-bad-lo end
            const int c2 = (131 - jj) - e2_0;     // mid-bad boundary
            const int lo2 = c2 < rw ? c2 : rw;
            const int hi2 = c2 < rw ? rw : c2;
            u64 colm = ~(bitrange(0, c1) | bitrange(lo2, hi2));
            u64 rowm = (rok1 ? bitrange(0, rw) : 0ull) | (rok2 ? bitrange(rw, 49) : 0ull);
            u64 vm = (colm & rowm) >> (kg << 2);  // bit (16mt+r) now compile-time
            const u32 vlo = (u32)vm, vhi = (u32)(vm >> 32);

            #pragma unroll
            for (int mt = 0; mt < 4; ++mt)
                #pragma unroll
                for (int r = 0; r < 4; ++r) {
                    int rr = 16 * mt + 4 * kg + r;
                    if (rr < R) {
                        const int bp = 16 * mt + r;           // compile-time
                        bool ok = (((bp < 32 ? vlo : vhi) >> (bp & 31)) & 1u) != 0;
                        wv[mt][r] = ok ? wv[mt][r] * inv : 0.0f;
                    }
                }

            #pragma unroll
            for (int mt = 0; mt < 4; ++mt)
                #pragma unroll
                for (int jp = 0; jp < 2; ++jp) {
                    int j = 8 * mt + 2 * kg + jp;
                    if (j <= 24) {
                        u32 pk = (u32)(unsigned short)f2bf(wv[mt][2 * jp])
                               | ((u32)(unsigned short)f2bf(wv[mt][2 * jp + 1]) << 16);
                        wpack[j * CH + chh] = pk;
                    }
                }
        }
    }
    __syncthreads();          // hid dead (win overlay ok), wpack visible

    st();                     // stage batch 0 into win (linear)

    // ---------- per-thread weights: pw[26] -> parity-shifted qw[28] ----------
    float qw[28];
    {
        const int j0 = g ? 13 : 0;
        const int nj = g ? 12 : 13;
        u32 wr[13];
        #pragma unroll
        for (int i = 0; i < 13; ++i) wr[i] = (i < nj) ? wpack[(j0 + i) * CH + ch] : 0u;
        float pw[26];
        #pragma unroll
        for (int i = 0; i < 13; ++i) {
            pw[2 * i]     = bf2f_u(wr[i] & 0xffffu);
            pw[2 * i + 1] = bf2f_u(wr[i] >> 16);
        }
        const int kw0 = g ? 26 : 0;
        const int par = (m2v + 49 * ch + kw0) & 1;
        #pragma unroll
        for (int k2 = 0; k2 < 28; ++k2) {
            float a_ = (k2 < 26) ? pw[k2] : 0.0f;
            float b_ = (k2 >= 1 && k2 <= 26) ? pw[k2 - 1] : 0.0f;
            qw[k2] = par ? b_ : a_;
        }
    }
    const int d0 = m3 + ((m2v + 49 * ch + (g ? 26 : 0)) >> 1);
    __syncthreads();          // st(0) done

    // ---------- batch loop: 14 linear LDS dwords + 28 fma per thread ----------
    for (int b = 0; b < BS; ++b) {
        if (b + 1 < BS) ld(b + 1);               // issue early (T14)

        float acc2 = 0.0f;
        #pragma unroll
        for (int dd = 0; dd < 14; ++dd) {
            u32 wd = win[d0 + dd];               // base + imm offset (ds_read2 merge)
            acc2 = fmaf(__uint_as_float(wd << 16),         qw[2 * dd],     acc2);
            acc2 = fmaf(__uint_as_float(wd & 0xffff0000u), qw[2 * dd + 1], acc2);
        }
        if (g) part_s[ch] = acc2;
        __syncthreads();                          // win reads done + part_s visible
        if (!g) trb[((size_t)b * NPOS + pos) * CH + ch] = acc2 + part_s[ch];
        if (b + 1 < BS) st();                     // write late
        __syncthreads();                          // win ready for next batch
    }
}

// ---------- transpose (b,pos,ch) -> (b,ch,pos) ----------
__global__ __launch_bounds__(256) void poatt_tr(
    const float* __restrict__ ws, float* __restrict__ out)
{
    __shared__ float t[64 * 129];
    const int blk = blockIdx.x;
    const int b   = blk / 49;
    const int p0  = (blk % 49) * 64;
    const int tid = threadIdx.x;

    const int chR = tid & 127, pR = tid >> 7;
    #pragma unroll
    for (int r = 0; r < 32; ++r) {
        int pl = pR + 2 * r;
        t[pl * 129 + chR] = ws[((size_t)b * NPOS + p0 + pl) * CH + chR];
    }
    __syncthreads();
    const int pW = tid & 63, chW0 = tid >> 6;
    #pragma unroll
    for (int c = 0; c < 32; ++c) {
        int chl = chW0 + 4 * c;
        out[((size_t)b * CH + chl) * NPOS + p0 + pW] = t[pW * 129 + chl];
    }
}

// ================= fallback: monolithic kernel (round-4 proven) =================
template<bool WS_W2, bool USE_WS>
__global__ __launch_bounds__(256, 4) void poatt_mono(
    const float* __restrict__ x,
    const float* __restrict__ W1, const float* __restrict__ b1,
    const float* __restrict__ W2,
    const short* __restrict__ wsH, const short* __restrict__ wsL,
    float* __restrict__ dst)
{
    __shared__ float rel_s[R][2];
    __shared__ __align__(16) char smem[2 * 64 * HSTR * 2];
    short* hidH = (short*)smem;
    short* hidL = hidH + 64 * HSTR;
    float* Pbuf = (float*)smem;

    const int pos = blockIdx.x;
    const int tid = threadIdx.x;
    const int ch  = tid & (CH - 1);
    const int g   = tid >> 7;

    const int q  = pos >> 6;
    const int ii = q / KS;
    const int jj = q % KS;

    if (tid < 2 * R) {
        const int e  = (tid >= R) ? 1 : 0;
        const int rr = tid - e * R;
        int F  = (pos * 2 + e) * R + rr;
        int ep = F & 1;
        int t  = F >> 1;
        int jp = t % HH; t /= HH;
        int a  = t % HH; t /= HH;
        int jc = t % KS;
        int ic = t / KS;
        int row = jp + ic - 3;
        int col = ep + jc - 3;
        float v = 0.0f;
        if (row >= 0 && row < HH && (col == 0 || col == 1)) {
            int f    = a * (HH * 2) + row * 2 + col;
            int cidx = f / NPOS;
            int p    = f - cidx * NPOS;
            int u    = (cidx == 0) ? (p / HH) : (p % HH);
            v = -3.0f + 6.0f * (float)u * (1.0f / 55.0f);
        }
        const float c0 = -3.0f + 6.0f * (float)(pos / HH) * (1.0f / 55.0f);
        const float c1 = -3.0f + 6.0f * (float)(pos % HH) * (1.0f / 55.0f);
        rel_s[rr][e] = v - ((e == 0) ? c0 : c1);
    }
    __syncthreads();

    {
        const float w10 = W1[ch];
        const float w11 = W1[CH + ch];
        const float bb  = b1[ch];
        for (int rr = g; rr < R; rr += 2) {
            float h = fmaf(rel_s[rr][0], w10, fmaf(rel_s[rr][1], w11, bb));
            h = fmaxf(h, 0.0f);
            short hi = f2bf(h);
            hidH[rr * HSTR + ch] = hi;
            hidL[rr * HSTR + ch] = f2bf(h - bf2f(hi));
        }
        for (int t = tid; t < 15 * HSTR; t += 256) {
            hidH[R * HSTR + t] = 0;
            hidL[R * HSTR + t] = 0;
        }
    }
    __syncthreads();

    {
        const int w  = tid >> 6;
        const int l  = tid & 63;
        const int lr = l & 15;
        const int kg = l >> 4;

        short8 aH[4], aL[4];
        const int abase = (16 * w + lr) * HSTR + kg * 8;
        #pragma unroll
        for (int kk = 0; kk < 4; ++kk) {
            aH[kk] = *reinterpret_cast<const short8*>(&hidH[abase + kk * 32]);
            aL[kk] = *reinterpret_cast<const short8*>(&hidL[abase + kk * 32]);
        }

        f32x4 acc[8];
        #pragma unroll
        for (int n = 0; n < 8; ++n) acc[n] = (f32x4)0.0f;

        #pragma unroll
        for (int n = 0; n < 8; ++n) {
            const int bcol = 16 * n + lr;
            #pragma unroll
            for (int kk = 0; kk < 4; ++kk) {
                short8 bH, bL;
                if (WS_W2) {
                    bH = *reinterpret_cast<const short8*>(wsH + bcol * CH + kk * 32 + kg * 8);
                    bL = *reinterpret_cast<const short8*>(wsL + bcol * CH + kk * 32 + kg * 8);
                } else {
                    #pragma unroll
                    for (int j = 0; j < 8; ++j) {
                        float ww = ((const float*)W2)[(kk * 32 + kg * 8 + j) * CH + bcol];
                        short hi = f2bf(ww);
                        bH[j] = hi;
                        bL[j] = f2bf(ww - bf2f(hi));
                    }
                }
                acc[n] = __builtin_amdgcn_mfma_f32_16x16x32_bf16(aL[kk], bH, acc[n], 0, 0, 0);
                acc[n] = __builtin_amdgcn_mfma_f32_16x16x32_bf16(aH[kk], bL, acc[n], 0, 0, 0);
                acc[n] = __builtin_amdgcn_mfma_f32_16x16x32_bf16(aH[kk], bH, acc[n], 0, 0, 0);
            }
        }
        __syncthreads();

        #pragma unroll
        for (int n = 0; n < 8; ++n) {
            #pragma unroll
            for (int r = 0; r < 4; ++r) {
                int rr = 16 * w + kg * 4 + r;
                if (rr < R) Pbuf[rr * PSTR + 16 * n + lr] = acc[n][r];
            }
        }
    }
    __syncthreads();

    if (tid < CH) {
        float p[R];
        #pragma unroll
        for (int rr = 0; rr < R; ++rr) p[rr] = Pbuf[rr * PSTR + tid];
        float mx = p[0];
        #pragma unroll
        for (int rr = 1; rr < R; ++rr) mx = fmaxf(mx, p[rr]);
        float s = 0.0f;
        #pragma unroll
        for (int rr = 0; rr < R; ++rr) { p[rr] = __expf(p[rr] - mx); s += p[rr]; }
        const float inv = 1.0f / s;
        const int wb0 = (pos & 63) * (R * CH);
        #pragma unroll
        for (int rr = 0; rr < R; ++rr) {
            int rem = wb0 + tid * R + rr;
            int e2  = rem & (CH - 1);
            int j2  = (rem >> 7) % HH;
            int row = j2 + ii - 3;
            int col = e2 + jj - 3;
            bool valid = (row >= 0) && (row < HH) && (col >= 0) && (col < CH);
            Pbuf[rr * PSTR + tid] = valid ? p[rr] * inv : 0.0f;
        }
    }
    __syncthreads();

    float p[R];
    #pragma unroll
    for (int rr = 0; rr < R; ++rr) p[rr] = Pbuf[rr * PSTR + ch];

    const int winbase = (pos & 63) * (R * CH) + (ii - 3) * CH + (jj - 3);
    const int base_t  = winbase + ch * R;

    #pragma unroll
    for (int bi = 0; bi < 4; ++bi) {
        const int b  = g * 4 + bi;
        const int ab = b * XSTR + base_t;
        const bool safe = (b > 0 || winbase >= 0) && (b < BS - 1 || winbase + R * CH <= XSTR);
        float acc = 0.0f;
        if (safe) {
            #pragma unroll
            for (int rr = 0; rr < R; ++rr) acc = fmaf(p[rr], x[ab + rr], acc);
        } else {
            #pragma unroll
            for (int rr = 0; rr < R; ++rr) {
                int a2 = ab + rr;
                a2 = a2 < 0 ? 0 : (a2 >= XTOT ? XTOT - 1 : a2);
                acc = fmaf(p[rr], x[a2], acc);
            }
        }
        if (USE_WS) dst[((size_t)b * NPOS + pos) * CH + ch] = acc;
        else        dst[((size_t)b * CH + ch) * NPOS + pos] = acc;
    }
}

extern "C" void kernel_launch(void* const* d_in, const int* in_sizes, int n_in,
                              void* d_out, int out_size, void* d_ws, size_t ws_size,
                              hipStream_t stream) {
    (void)in_sizes; (void)n_in; (void)out_size;
    const float* x  = (const float*)d_in[0];
    const float* W1 = (const float*)d_in[1];
    const float* b1 = (const float*)d_in[2];
    const float* W2 = (const float*)d_in[3];
    float* out = (float*)d_out;

    // ws layout: [W2T hi/lo 64KB][x2 bf16 6.125MB][trb 12.25MB]
    const size_t W2T_BYTES = 2u * CH * CH * sizeof(short);            //    65536
    const size_t X2_BYTES  = (size_t)XTOT * 2;                        //  6422528
    const size_t TRB_BYTES = (size_t)BS * NPOS * CH * sizeof(float);  // 12845056
    const size_t FULL = W2T_BYTES + X2_BYTES + TRB_BYTES;             // 19333120

    short* wsH = (short*)d_ws;
    short* wsL = wsH + CH * CH;

    if (ws_size >= FULL) {
        u32*   x2  = (u32*)((char*)d_ws + W2T_BYTES);
        float* trb = (float*)((char*)d_ws + W2T_BYTES + X2_BYTES);

        poatt_pc<<<dim3(XTOT / (256 * 8)), dim3(256), 0, stream>>>(x, W2, x2, wsH, wsL);
        poatt_fused<<<dim3(NPOS), dim3(256), 0, stream>>>(x2, W1, b1, wsH, wsL, trb);
        poatt_tr<<<dim3(BS * 49), dim3(256), 0, stream>>>(trb, out);
    } else if (ws_size >= W2T_BYTES + TRB_BYTES) {
        float* trb = (float*)((char*)d_ws + W2T_BYTES);
        poatt_prep<<<dim3(64), dim3(256), 0, stream>>>(W2, wsH, wsL);
        poatt_mono<true, true><<<dim3(NPOS), dim3(256), 0, stream>>>(
            x, W1, b1, W2, wsH, wsL, trb);
        poatt_tr<<<dim3(BS * 49), dim3(256), 0, stream>>>(trb, out);
    } else if (ws_size >= W2T_BYTES) {
        poatt_prep<<<dim3(64), dim3(256), 0, stream>>>(W2, wsH, wsL);
        poatt_mono<true, false><<<dim3(NPOS), dim3(256), 0, stream>>>(
            x, W1, b1, W2, wsH, wsL, out);
    } else {
        poatt_mono<false, false><<<dim3(NPOS), dim3(256), 0, stream>>>(
            x, W1, b1, W2, nullptr, nullptr, out);
    }
}

// Round 12
// 71.084 us; speedup vs baseline: 1.2257x; 1.0626x over previous
//
#include <hip/hip_runtime.h>

#define CH   128
#define KS   7
#define R    49
#define HH   56
#define NPOS 3136
#define BS   8
#define XSTR 401408
#define XTOT (BS*XSTR)

typedef short short8 __attribute__((ext_vector_type(8)));
typedef float f32x4  __attribute__((ext_vector_type(4)));
typedef unsigned int u32;
typedef unsigned long long u64;
typedef u32 u32x4 __attribute__((ext_vector_type(4)));

__device__ __forceinline__ short f2bf(float f) {            // RNE fp32->bf16
    unsigned u = __float_as_uint(f);
    u += 0x7fffu + ((u >> 16) & 1u);
    return (short)(u >> 16);
}
__device__ __forceinline__ float bf2f(short s) {
    return __uint_as_float(((unsigned)(unsigned short)s) << 16);
}
__device__ __forceinline__ float bf2f_u(u32 lo16) {
    return __uint_as_float(lo16 << 16);
}
__device__ __forceinline__ u64 bitrange(int a, int b) {     // bits [a,b) clamped to [0,49]
    a = a < 0 ? 0 : (a > 49 ? 49 : a);
    b = b < 0 ? 0 : (b > 49 ? 49 : b);
    if (b <= a) return 0ull;
    return (1ull << b) - (1ull << a);
}

#define HSTR 136            // hid LDS row stride (bf16 elems)
#define PSTR 132            // P LDS row stride (fp32) - mono fallback only
#define NWIN 3140           // win dwords (785 u32x4 chunks)

// ---------- prep (fallback path only) ----------
__global__ __launch_bounds__(256) void poatt_prep(
    const float* __restrict__ W2, short* __restrict__ wsH, short* __restrict__ wsL)
{
    int t = blockIdx.x * 256 + threadIdx.x;
    int k = t >> 7, ch = t & 127;
    float w = W2[k * CH + ch];
    short hi = f2bf(w);
    wsH[ch * CH + k] = hi;
    wsL[ch * CH + k] = f2bf(w - bf2f(hi));
}

// ---------- combined: cvt x->bf16 pairs + W2 prep (first 64 blocks) ----------
__global__ __launch_bounds__(256) void poatt_pc(
    const float* __restrict__ x, const float* __restrict__ W2,
    u32* __restrict__ x2, short* __restrict__ wsH, short* __restrict__ wsL)
{
    int t = blockIdx.x * 256 + threadIdx.x;      // grid 1568
    const float4* xv = reinterpret_cast<const float4*>(x);
    float4 a = xv[2 * t], b = xv[2 * t + 1];
    u32x4 o;
    o[0] = (u32)(unsigned short)f2bf(a.x) | ((u32)(unsigned short)f2bf(a.y) << 16);
    o[1] = (u32)(unsigned short)f2bf(a.z) | ((u32)(unsigned short)f2bf(a.w) << 16);
    o[2] = (u32)(unsigned short)f2bf(b.x) | ((u32)(unsigned short)f2bf(b.y) << 16);
    o[3] = (u32)(unsigned short)f2bf(b.z) | ((u32)(unsigned short)f2bf(b.w) << 16);
    reinterpret_cast<u32x4*>(x2)[t] = o;

    if (t < CH * CH) {
        int k = t >> 7, ch = t & 127;
        float w = W2[k * CH + ch];
        short hi = f2bf(w);
        wsH[ch * CH + k] = hi;
        wsL[ch * CH + k] = f2bf(w - bf2f(hi));
    }
}

// ---------- fused: weights (MFMA + in-reg softmax) + 8-batch dbuf apply ----------
__global__ __launch_bounds__(256, 4) void poatt_fused(
    const u32* __restrict__ x2,
    const float* __restrict__ W1, const float* __restrict__ b1,
    const short* __restrict__ wsH, const short* __restrict__ wsL,
    float* __restrict__ trb)         // (b,pos,ch)
{
    __shared__ float rel_s[R][2];
    __shared__ float part_s[2][CH];
    __shared__ u32 wpack[25 * CH];                    // 12800 B: weights, then win1
    __shared__ __align__(16) char smem[64 * HSTR * 2];// 17408 B: hid, then win0
    short* hid_s = (short*)smem;
    u32*   win0  = (u32*)smem;                        // overlays hid
    u32*   win1  = wpack;                             // overlays wpack

    const int pos = blockIdx.x;                       // natural: XCD = s mod 8
    const int tid = threadIdx.x;
    const int ch  = tid & (CH - 1);
    const int g   = tid >> 7;

    const int q  = pos >> 6;
    const int s  = pos & 63;
    const int ii = q / KS;
    const int jj = q % KS;

    // ---------- phase 0: rel ----------
    if (tid < 2 * R) {
        const int e  = (tid >= R) ? 1 : 0;
        const int rr = tid - e * R;
        int F  = (pos * 2 + e) * R + rr;
        int ep = F & 1;
        int t  = F >> 1;
        int jp = t % HH; t /= HH;
        int a  = t % HH; t /= HH;
        int jc = t % KS;
        int ic = t / KS;
        int row = jp + ic - 3;
        int col = ep + jc - 3;
        float v = 0.0f;
        if (row >= 0 && row < HH && (col == 0 || col == 1)) {
            int f    = a * (HH * 2) + row * 2 + col;
            int cidx = f / NPOS;
            int p    = f - cidx * NPOS;
            int u    = (cidx == 0) ? (p / HH) : (p % HH);
            v = -3.0f + 6.0f * (float)u * (1.0f / 55.0f);
        }
        const float c0 = -3.0f + 6.0f * (float)(pos / HH) * (1.0f / 55.0f);
        const float c1 = -3.0f + 6.0f * (float)(pos % HH) * (1.0f / 55.0f);
        rel_s[rr][e] = v - ((e == 0) ? c0 : c1);
    }
    __syncthreads();

    // ---------- phase 1: hid = relu(rel@W1+b1) -> bf16 LDS ----------
    {
        const float w10 = W1[ch];
        const float w11 = W1[CH + ch];
        const float bb  = b1[ch];
        for (int rr = g; rr < R; rr += 2) {
            float h = fmaf(rel_s[rr][0], w10, fmaf(rel_s[rr][1], w11, bb));
            hid_s[rr * HSTR + ch] = f2bf(fmaxf(h, 0.0f));
        }
        for (int t = tid; t < 15 * HSTR; t += 256) hid_s[R * HSTR + t] = 0;
    }
    __syncthreads();

    // ---------- window geometry ----------
    const int winbase = s * (R * CH) + (ii - 3) * CH + (jj - 3);
    const int m2v = winbase & 1;
    const int hw  = winbase >> 1;
    const int m3  = hw & 3;
    const int cw0 = (hw - m3) >> 2;               // u32x4 chunk base (batch plane)
    const u32x4* x2v = reinterpret_cast<const u32x4*>(x2);
    const unsigned short* x2s = reinterpret_cast<const unsigned short*>(x2);

    u32x4 v[4];
    auto ld = [&](int b) {
        const int cb = b * (XSTR >> 3) + cw0;
        const bool safe = (b > 0 || winbase >= 8) && (b < BS - 1 || winbase + 6280 <= XSTR);
        if (safe) {
            v[0] = x2v[cb + tid];
            v[1] = x2v[cb + tid + 256];
            v[2] = x2v[cb + tid + 512];
            if (tid < 17) v[3] = x2v[cb + tid + 768];
        } else {
            #pragma unroll
            for (int j = 0; j < 4; ++j) {
                if (j < 3 || tid < 17) {
                    int gc = cb + tid + 256 * j;
                    u32x4 o;
                    #pragma unroll
                    for (int kk = 0; kk < 4; ++kk) {
                        int e0 = 8 * gc + 2 * kk;
                        int a0 = e0;     a0 = a0 < 0 ? 0 : (a0 >= XTOT ? XTOT - 1 : a0);
                        int a1 = e0 + 1; a1 = a1 < 0 ? 0 : (a1 >= XTOT ? XTOT - 1 : a1);
                        o[kk] = (u32)x2s[a0] | ((u32)x2s[a1] << 16);  // masked (w=0)
                    }
                    v[j] = o;
                }
            }
        }
    };
    auto st = [&](u32* wb) {   // linear layout, 4x ds_write_b128, conflict-free
        *reinterpret_cast<u32x4*>(&wb[4 * tid])         = v[0];
        *reinterpret_cast<u32x4*>(&wb[4 * (tid + 256)]) = v[1];
        *reinterpret_cast<u32x4*>(&wb[4 * (tid + 512)]) = v[2];
        if (tid < 17)
            *reinterpret_cast<u32x4*>(&wb[4 * (tid + 768)]) = v[3];
    };

    ld(0);   // batch-0 loads in flight across the MFMA phase

    // ---------- phase 2: P columns [32w,32w+32), kk-outer (A-frags shared) ----------
    const int wv_ = tid >> 6;
    const int l   = tid & 63;
    const int lr  = l & 15;
    const int kg  = l >> 4;

    f32x4 acc[4][2];
    #pragma unroll
    for (int mt = 0; mt < 4; ++mt) { acc[mt][0] = (f32x4)0.0f; acc[mt][1] = (f32x4)0.0f; }

    #pragma unroll
    for (int kk = 0; kk < 4; ++kk) {
        short8 aF[4];
        #pragma unroll
        for (int mt = 0; mt < 4; ++mt)
            aF[mt] = *reinterpret_cast<const short8*>(
                &hid_s[(16 * mt + lr) * HSTR + kk * 32 + kg * 8]);
        #pragma unroll
        for (int np = 0; np < 2; ++np) {
            const int bcol = 32 * wv_ + 16 * np + lr;
            short8 bH = *reinterpret_cast<const short8*>(wsH + bcol * CH + kk * 32 + kg * 8);
            short8 bL = *reinterpret_cast<const short8*>(wsL + bcol * CH + kk * 32 + kg * 8);
            #pragma unroll
            for (int mt = 0; mt < 4; ++mt) {
                acc[mt][np] = __builtin_amdgcn_mfma_f32_16x16x32_bf16(aF[mt], bH, acc[mt][np], 0, 0, 0);
                acc[mt][np] = __builtin_amdgcn_mfma_f32_16x16x32_bf16(aF[mt], bL, acc[mt][np], 0, 0, 0);
            }
        }
    }

    // ---------- phase 3: in-reg softmax + interval-bitmask mask -> wpack ----------
    {
        float wv[4][4];
        #pragma unroll
        for (int np = 0; np < 2; ++np) {
            const int chh = 32 * wv_ + 16 * np + lr;

            float mx = -1e30f;
            #pragma unroll
            for (int mt = 0; mt < 4; ++mt)
                #pragma unroll
                for (int r = 0; r < 4; ++r) {
                    int rr = 16 * mt + 4 * kg + r;
                    if (rr < R) mx = fmaxf(mx, acc[mt][np][r]);
                }
            mx = fmaxf(mx, __shfl_xor(mx, 16));
            mx = fmaxf(mx, __shfl_xor(mx, 32));

            float sm = 0.0f;
            #pragma unroll
            for (int mt = 0; mt < 4; ++mt)
                #pragma unroll
                for (int r = 0; r < 4; ++r) {
                    int rr = 16 * mt + 4 * kg + r;
                    float e = (rr < R) ? __expf(acc[mt][np][r] - mx) : 0.0f;
                    wv[mt][r] = e;
                    sm += e;
                }
            sm += __shfl_xor(sm, 16);
            sm += __shfl_xor(sm, 32);
            const float inv = 1.0f / sm;

            // validity bitmask over rr in [0,49)
            const int base = s * (R * CH) + chh * R;
            const int e2_0 = base & 127;
            const int jb   = base >> 7;
            const int j2_0 = jb % HH;
            const int rw   = 128 - e2_0;
            int j2p = j2_0 + 1; if (j2p == HH) j2p = 0;
            const bool rok1 = (j2_0 >= 3 - ii) && (j2_0 < 59 - ii);
            const bool rok2 = (j2p  >= 3 - ii) && (j2p  < 59 - ii);
            const int c1 = (3 - jj) - e2_0;
            const int c2 = (131 - jj) - e2_0;
            const int lo2 = c2 < rw ? c2 : rw;
            const int hi2 = c2 < rw ? rw : c2;
            u64 colm = ~(bitrange(0, c1) | bitrange(lo2, hi2));
            u64 rowm = (rok1 ? bitrange(0, rw) : 0ull) | (rok2 ? bitrange(rw, 49) : 0ull);
            u64 vm = (colm & rowm) >> (kg << 2);
            const u32 vlo = (u32)vm, vhi = (u32)(vm >> 32);

            #pragma unroll
            for (int mt = 0; mt < 4; ++mt)
                #pragma unroll
                for (int r = 0; r < 4; ++r) {
                    int rr = 16 * mt + 4 * kg + r;
                    if (rr < R) {
                        const int bp = 16 * mt + r;
                        bool ok = (((bp < 32 ? vlo : vhi) >> (bp & 31)) & 1u) != 0;
                        wv[mt][r] = ok ? wv[mt][r] * inv : 0.0f;
                    }
                }

            #pragma unroll
            for (int mt = 0; mt < 4; ++mt)
                #pragma unroll
                for (int jp = 0; jp < 2; ++jp) {
                    int j = 8 * mt + 2 * kg + jp;
                    if (j <= 24) {
                        u32 pk = (u32)(unsigned short)f2bf(wv[mt][2 * jp])
                               | ((u32)(unsigned short)f2bf(wv[mt][2 * jp + 1]) << 16);
                        wpack[j * CH + chh] = pk;
                    }
                }
        }
    }
    __syncthreads();          // hid dead (win0 overlay ok), wpack visible

    // ---------- per-thread weights: pw[26] -> parity-shifted qw[28] ----------
    float qw[28];
    {
        const int j0 = g ? 13 : 0;
        const int nj = g ? 12 : 13;
        u32 wr[13];
        #pragma unroll
        for (int i = 0; i < 13; ++i) wr[i] = (i < nj) ? wpack[(j0 + i) * CH + ch] : 0u;
        float pw[26];
        #pragma unroll
        for (int i = 0; i < 13; ++i) {
            pw[2 * i]     = bf2f_u(wr[i] & 0xffffu);
            pw[2 * i + 1] = bf2f_u(wr[i] >> 16);
        }
        const int kw0 = g ? 26 : 0;
        const int par = (m2v + 49 * ch + kw0) & 1;
        #pragma unroll
        for (int k2 = 0; k2 < 28; ++k2) {
            float a_ = (k2 < 26) ? pw[k2] : 0.0f;
            float b_ = (k2 >= 1 && k2 <= 26) ? pw[k2 - 1] : 0.0f;
            qw[k2] = par ? b_ : a_;
        }
    }
    const int d0 = m3 + ((m2v + 49 * ch + (g ? 26 : 0)) >> 1);

    st(win0);                 // batch 0 -> win0 (hid dead; wpack reads done above)
    ld(1);                    // batch-1 loads in flight
    __syncthreads();          // win0 visible; all wpack reads complete (before any win1 write)

    // ---------- batch loop: double-buffered, ONE barrier per batch ----------
    #pragma unroll
    for (int b = 0; b < BS; ++b) {
        const u32* wb = (b & 1) ? win1 : win0;

        float acc2 = 0.0f;
        #pragma unroll
        for (int dd = 0; dd < 14; ++dd) {
            u32 wd = wb[d0 + dd];                // base + imm offset
            acc2 = fmaf(__uint_as_float(wd << 16),         qw[2 * dd],     acc2);
            acc2 = fmaf(__uint_as_float(wd & 0xffff0000u), qw[2 * dd + 1], acc2);
        }

        if (b + 1 < BS) st((b & 1) ? win0 : win1);   // stage next batch into OTHER buf
        if (b + 2 < BS) ld(b + 2);                   // issue loads 2 batches ahead

        if (g) part_s[b & 1][ch] = acc2;
        __syncthreads();                              // next buf + part_s visible
        if (!g) trb[((size_t)b * NPOS + pos) * CH + ch] = acc2 + part_s[b & 1][ch];
    }
}

// ---------- transpose (b,pos,ch) -> (b,ch,pos) ----------
__global__ __launch_bounds__(256) void poatt_tr(
    const float* __restrict__ ws, float* __restrict__ out)
{
    __shared__ float t[64 * 129];
    const int blk = blockIdx.x;
    const int b   = blk / 49;
    const int p0  = (blk % 49) * 64;
    const int tid = threadIdx.x;

    const int chR = tid & 127, pR = tid >> 7;
    #pragma unroll
    for (int r = 0; r < 32; ++r) {
        int pl = pR + 2 * r;
        t[pl * 129 + chR] = ws[((size_t)b * NPOS + p0 + pl) * CH + chR];
    }
    __syncthreads();
    const int pW = tid & 63, chW0 = tid >> 6;
    #pragma unroll
    for (int c = 0; c < 32; ++c) {
        int chl = chW0 + 4 * c;
        out[((size_t)b * CH + chl) * NPOS + p0 + pW] = t[pW * 129 + chl];
    }
}

// ================= fallback: monolithic kernel (round-4 proven) =================
template<bool WS_W2, bool USE_WS>
__global__ __launch_bounds__(256, 4) void poatt_mono(
    const float* __restrict__ x,
    const float* __restrict__ W1, const float* __restrict__ b1,
    const float* __restrict__ W2,
    const short* __restrict__ wsH, const short* __restrict__ wsL,
    float* __restrict__ dst)
{
    __shared__ float rel_s[R][2];
    __shared__ __align__(16) char smem[2 * 64 * HSTR * 2];
    short* hidH = (short*)smem;
    short* hidL = hidH + 64 * HSTR;
    float* Pbuf = (float*)smem;

    const int pos = blockIdx.x;
    const int tid = threadIdx.x;
    const int ch  = tid & (CH - 1);
    const int g   = tid >> 7;

    const int q  = pos >> 6;
    const int ii = q / KS;
    const int jj = q % KS;

    if (tid < 2 * R) {
        const int e  = (tid >= R) ? 1 : 0;
        const int rr = tid - e * R;
        int F  = (pos * 2 + e) * R + rr;
        int ep = F & 1;
        int t  = F >> 1;
        int jp = t % HH; t /= HH;
        int a  = t % HH; t /= HH;
        int jc = t % KS;
        int ic = t / KS;
        int row = jp + ic - 3;
        int col = ep + jc - 3;
        float v = 0.0f;
        if (row >= 0 && row < HH && (col == 0 || col == 1)) {
            int f    = a * (HH * 2) + row * 2 + col;
            int cidx = f / NPOS;
            int p    = f - cidx * NPOS;
            int u    = (cidx == 0) ? (p / HH) : (p % HH);
            v = -3.0f + 6.0f * (float)u * (1.0f / 55.0f);
        }
        const float c0 = -3.0f + 6.0f * (float)(pos / HH) * (1.0f / 55.0f);
        const float c1 = -3.0f + 6.0f * (float)(pos % HH) * (1.0f / 55.0f);
        rel_s[rr][e] = v - ((e == 0) ? c0 : c1);
    }
    __syncthreads();

    {
        const float w10 = W1[ch];
        const float w11 = W1[CH + ch];
        const float bb  = b1[ch];
        for (int rr = g; rr < R; rr += 2) {
            float h = fmaf(rel_s[rr][0], w10, fmaf(rel_s[rr][1], w11, bb));
            h = fmaxf(h, 0.0f);
            short hi = f2bf(h);
            hidH[rr * HSTR + ch] = hi;
            hidL[rr * HSTR + ch] = f2bf(h - bf2f(hi));
        }
        for (int t = tid; t < 15 * HSTR; t += 256) {
            hidH[R * HSTR + t] = 0;
            hidL[R * HSTR + t] = 0;
        }
    }
    __syncthreads();

    {
        const int w  = tid >> 6;
        const int l  = tid & 63;
        const int lr = l & 15;
        const int kg = l >> 4;

        short8 aH[4], aL[4];
        const int abase = (16 * w + lr) * HSTR + kg * 8;
        #pragma unroll
        for (int kk = 0; kk < 4; ++kk) {
            aH[kk] = *reinterpret_cast<const short8*>(&hidH[abase + kk * 32]);
            aL[kk] = *reinterpret_cast<const short8*>(&hidL[abase + kk * 32]);
        }

        f32x4 acc[8];
        #pragma unroll
        for (int n = 0; n < 8; ++n) acc[n] = (f32x4)0.0f;

        #pragma unroll
        for (int n = 0; n < 8; ++n) {
            const int bcol = 16 * n + lr;
            #pragma unroll
            for (int kk = 0; kk < 4; ++kk) {
                short8 bH, bL;
                if (WS_W2) {
                    bH = *reinterpret_cast<const short8*>(wsH + bcol * CH + kk * 32 + kg * 8);
                    bL = *reinterpret_cast<const short8*>(wsL + bcol * CH + kk * 32 + kg * 8);
                } else {
                    #pragma unroll
                    for (int j = 0; j < 8; ++j) {
                        float ww = ((const float*)W2)[(kk * 32 + kg * 8 + j) * CH + bcol];
                        short hi = f2bf(ww);
                        bH[j] = hi;
                        bL[j] = f2bf(ww - bf2f(hi));
                    }
                }
                acc[n] = __builtin_amdgcn_mfma_f32_16x16x32_bf16(aL[kk], bH, acc[n], 0, 0, 0);
                acc[n] = __builtin_amdgcn_mfma_f32_16x16x32_bf16(aH[kk], bL, acc[n], 0, 0, 0);
                acc[n] = __builtin_amdgcn_mfma_f32_16x16x32_bf16(aH[kk], bH, acc[n], 0, 0, 0);
            }
        }
        __syncthreads();

        #pragma unroll
        for (int n = 0; n < 8; ++n) {
            #pragma unroll
            for (int r = 0; r < 4; ++r) {
                int rr = 16 * w + kg * 4 + r;
                if (rr < R) Pbuf[rr * PSTR + 16 * n + lr] = acc[n][r];
            }
        }
    }
    __syncthreads();

    if (tid < CH) {
        float p[R];
        #pragma unroll
        for (int rr = 0; rr < R; ++rr) p[rr] = Pbuf[rr * PSTR + tid];
        float mx = p[0];
        #pragma unroll
        for (int rr = 1; rr < R; ++rr) mx = fmaxf(mx, p[rr]);
        float s = 0.0f;
        #pragma unroll
        for (int rr = 0; rr < R; ++rr) { p[rr] = __expf(p[rr] - mx); s += p[rr]; }
        const float inv = 1.0f / s;
        const int wb0 = (pos & 63) * (R * CH);
        #pragma unroll
        for (int rr = 0; rr < R; ++rr) {
            int rem = wb0 + tid * R + rr;
            int e2  = rem & (CH - 1);
            int j2  = (rem >> 7) % HH;
            int row = j2 + ii - 3;
            int col = e2 + jj - 3;
            bool valid = (row >= 0) && (row < HH) && (col >= 0) && (col < CH);
            Pbuf[rr * PSTR + tid] = valid ? p[rr] * inv : 0.0f;
        }
    }
    __syncthreads();

    float p[R];
    #pragma unroll
    for (int rr = 0; rr < R; ++rr) p[rr] = Pbuf[rr * PSTR + ch];

    const int winbase = (pos & 63) * (R * CH) + (ii - 3) * CH + (jj - 3);
    const int base_t  = winbase + ch * R;

    #pragma unroll
    for (int bi = 0; bi < 4; ++bi) {
        const int b  = g * 4 + bi;
        const int ab = b * XSTR + base_t;
        const bool safe = (b > 0 || winbase >= 0) && (b < BS - 1 || winbase + R * CH <= XSTR);
        float acc = 0.0f;
        if (safe) {
            #pragma unroll
            for (int rr = 0; rr < R; ++rr) acc = fmaf(p[rr], x[ab + rr], acc);
        } else {
            #pragma unroll
            for (int rr = 0; rr < R; ++rr) {
                int a2 = ab + rr;
                a2 = a2 < 0 ? 0 : (a2 >= XTOT ? XTOT - 1 : a2);
                acc = fmaf(p[rr], x[a2], acc);
            }
        }
        if (USE_WS) dst[((size_t)b * NPOS + pos) * CH + ch] = acc;
        else        dst[((size_t)b * CH + ch) * NPOS + pos] = acc;
    }
}

extern "C" void kernel_launch(void* const* d_in, const int* in_sizes, int n_in,
                              void* d_out, int out_size, void* d_ws, size_t ws_size,
                              hipStream_t stream) {
    (void)in_sizes; (void)n_in; (void)out_size;
    const float* x  = (const float*)d_in[0];
    const float* W1 = (const float*)d_in[1];
    const float* b1 = (const float*)d_in[2];
    const float* W2 = (const float*)d_in[3];
    float* out = (float*)d_out;

    // ws layout: [W2T hi/lo 64KB][x2 bf16 6.125MB][trb 12.25MB]
    const size_t W2T_BYTES = 2u * CH * CH * sizeof(short);            //    65536
    const size_t X2_BYTES  = (size_t)XTOT * 2;                        //  6422528
    const size_t TRB_BYTES = (size_t)BS * NPOS * CH * sizeof(float);  // 12845056
    const size_t FULL = W2T_BYTES + X2_BYTES + TRB_BYTES;             // 19333120

    short* wsH = (short*)d_ws;
    short* wsL = wsH + CH * CH;

    if (ws_size >= FULL) {
        u32*   x2  = (u32*)((char*)d_ws + W2T_BYTES);
        float* trb = (float*)((char*)d_ws + W2T_BYTES + X2_BYTES);

        poatt_pc<<<dim3(XTOT / (256 * 8)), dim3(256), 0, stream>>>(x, W2, x2, wsH, wsL);
        poatt_fused<<<dim3(NPOS), dim3(256), 0, stream>>>(x2, W1, b1, wsH, wsL, trb);
        poatt_tr<<<dim3(BS * 49), dim3(256), 0, stream>>>(trb, out);
    } else if (ws_size >= W2T_BYTES + TRB_BYTES) {
        float* trb = (float*)((char*)d_ws + W2T_BYTES);
        poatt_prep<<<dim3(64), dim3(256), 0, stream>>>(W2, wsH, wsL);
        poatt_mono<true, true><<<dim3(NPOS), dim3(256), 0, stream>>>(
            x, W1, b1, W2, wsH, wsL, trb);
        poatt_tr<<<dim3(BS * 49), dim3(256), 0, stream>>>(trb, out);
    } else if (ws_size >= W2T_BYTES) {
        poatt_prep<<<dim3(64), dim3(256), 0, stream>>>(W2, wsH, wsL);
        poatt_mono<true, false><<<dim3(NPOS), dim3(256), 0, stream>>>(
            x, W1, b1, W2, wsH, wsL, out);
    } else {
        poatt_mono<false, false><<<dim3(NPOS), dim3(256), 0, stream>>>(
            x, W1, b1, W2, nullptr, nullptr, out);
    }
}

// Round 13
// 69.610 us; speedup vs baseline: 1.2516x; 1.0212x over previous
//
#include <hip/hip_runtime.h>

#define CH   128
#define KS   7
#define R    49
#define HH   56
#define NPOS 3136
#define BS   8
#define XSTR 401408
#define XTOT (BS*XSTR)

typedef short short8 __attribute__((ext_vector_type(8)));
typedef float f32x4  __attribute__((ext_vector_type(4)));
typedef unsigned int u32;
typedef unsigned long long u64;
typedef u32 u32x4 __attribute__((ext_vector_type(4)));
typedef __bf16 bf16x2 __attribute__((ext_vector_type(2)));

#if defined(__has_builtin)
#if __has_builtin(__builtin_amdgcn_fdot2_f32_bf16)
#define POATT_DOT2 1
#endif
#endif

__device__ __forceinline__ short f2bf(float f) {            // RNE fp32->bf16
    unsigned u = __float_as_uint(f);
    u += 0x7fffu + ((u >> 16) & 1u);
    return (short)(u >> 16);
}
__device__ __forceinline__ float bf2f(short s) {
    return __uint_as_float(((unsigned)(unsigned short)s) << 16);
}
__device__ __forceinline__ float bf2f_u(u32 lo16) {
    return __uint_as_float(lo16 << 16);
}
__device__ __forceinline__ u64 bitrange(int a, int b) {     // bits [a,b) clamped to [0,49]
    a = a < 0 ? 0 : (a > 49 ? 49 : a);
    b = b < 0 ? 0 : (b > 49 ? 49 : b);
    if (b <= a) return 0ull;
    return (1ull << b) - (1ull << a);
}

#define HSTR 136            // hid LDS row stride (bf16 elems)
#define PSTR 132            // P LDS row stride (fp32) - mono fallback only
#define NWIN 3140           // win dwords (785 u32x4 chunks)

// ---------- prep (fallback path only) ----------
__global__ __launch_bounds__(256) void poatt_prep(
    const float* __restrict__ W2, short* __restrict__ wsH, short* __restrict__ wsL)
{
    int t = blockIdx.x * 256 + threadIdx.x;
    int k = t >> 7, ch = t & 127;
    float w = W2[k * CH + ch];
    short hi = f2bf(w);
    wsH[ch * CH + k] = hi;
    wsL[ch * CH + k] = f2bf(w - bf2f(hi));
}

// ---------- combined: cvt x->bf16 pairs + W2 prep (first 64 blocks) ----------
__global__ __launch_bounds__(256) void poatt_pc(
    const float* __restrict__ x, const float* __restrict__ W2,
    u32* __restrict__ x2, short* __restrict__ wsH, short* __restrict__ wsL)
{
    int t = blockIdx.x * 256 + threadIdx.x;      // grid 1568
    const float4* xv = reinterpret_cast<const float4*>(x);
    float4 a = xv[2 * t], b = xv[2 * t + 1];
    u32x4 o;
    o[0] = (u32)(unsigned short)f2bf(a.x) | ((u32)(unsigned short)f2bf(a.y) << 16);
    o[1] = (u32)(unsigned short)f2bf(a.z) | ((u32)(unsigned short)f2bf(a.w) << 16);
    o[2] = (u32)(unsigned short)f2bf(b.x) | ((u32)(unsigned short)f2bf(b.y) << 16);
    o[3] = (u32)(unsigned short)f2bf(b.z) | ((u32)(unsigned short)f2bf(b.w) << 16);
    reinterpret_cast<u32x4*>(x2)[t] = o;

    if (t < CH * CH) {
        int k = t >> 7, ch = t & 127;
        float w = W2[k * CH + ch];
        short hi = f2bf(w);
        wsH[ch * CH + k] = hi;
        wsL[ch * CH + k] = f2bf(w - bf2f(hi));
    }
}

// ---------- fused: weights (MFMA + in-reg softmax) + 8-batch dbuf apply ----------
__global__ __launch_bounds__(256, 4) void poatt_fused(
    const u32* __restrict__ x2,
    const float* __restrict__ W1, const float* __restrict__ b1,
    const short* __restrict__ wsH, const short* __restrict__ wsL,
    float* __restrict__ trb)         // (b,pos,ch)
{
    __shared__ float rel_s[R][2];
    __shared__ float part_s[2][CH];
    __shared__ u32 wpack[25 * CH];                    // 12800 B: weights, then win1
    __shared__ __align__(16) char smem[64 * HSTR * 2];// 17408 B: hid, then win0
    short* hid_s = (short*)smem;
    u32*   win0  = (u32*)smem;                        // overlays hid
    u32*   win1  = wpack;                             // overlays wpack

    const int pos = blockIdx.x;                       // natural: XCD = s mod 8
    const int tid = threadIdx.x;
    const int ch  = tid & (CH - 1);
    const int g   = tid >> 7;

    const int q  = pos >> 6;
    const int s  = pos & 63;
    const int ii = q / KS;
    const int jj = q % KS;

    // ---------- phase 0: rel ----------
    if (tid < 2 * R) {
        const int e  = (tid >= R) ? 1 : 0;
        const int rr = tid - e * R;
        int F  = (pos * 2 + e) * R + rr;
        int ep = F & 1;
        int t  = F >> 1;
        int jp = t % HH; t /= HH;
        int a  = t % HH; t /= HH;
        int jc = t % KS;
        int ic = t / KS;
        int row = jp + ic - 3;
        int col = ep + jc - 3;
        float v = 0.0f;
        if (row >= 0 && row < HH && (col == 0 || col == 1)) {
            int f    = a * (HH * 2) + row * 2 + col;
            int cidx = f / NPOS;
            int p    = f - cidx * NPOS;
            int u    = (cidx == 0) ? (p / HH) : (p % HH);
            v = -3.0f + 6.0f * (float)u * (1.0f / 55.0f);
        }
        const float c0 = -3.0f + 6.0f * (float)(pos / HH) * (1.0f / 55.0f);
        const float c1 = -3.0f + 6.0f * (float)(pos % HH) * (1.0f / 55.0f);
        rel_s[rr][e] = v - ((e == 0) ? c0 : c1);
    }
    __syncthreads();

    // ---------- phase 1: hid = relu(rel@W1+b1) -> bf16 LDS ----------
    {
        const float w10 = W1[ch];
        const float w11 = W1[CH + ch];
        const float bb  = b1[ch];
        for (int rr = g; rr < R; rr += 2) {
            float h = fmaf(rel_s[rr][0], w10, fmaf(rel_s[rr][1], w11, bb));
            hid_s[rr * HSTR + ch] = f2bf(fmaxf(h, 0.0f));
        }
        for (int t = tid; t < 15 * HSTR; t += 256) hid_s[R * HSTR + t] = 0;
    }
    __syncthreads();

    // ---------- window geometry ----------
    const int winbase = s * (R * CH) + (ii - 3) * CH + (jj - 3);
    const int m2v = winbase & 1;
    const int hw  = winbase >> 1;
    const int m3  = hw & 3;
    const int cw0 = (hw - m3) >> 2;               // u32x4 chunk base (batch plane)
    const u32x4* x2v = reinterpret_cast<const u32x4*>(x2);
    const unsigned short* x2s = reinterpret_cast<const unsigned short*>(x2);

    u32x4 v[4];
    auto ld = [&](int b) {
        const int cb = b * (XSTR >> 3) + cw0;
        const bool safe = (b > 0 || winbase >= 8) && (b < BS - 1 || winbase + 6280 <= XSTR);
        if (safe) {
            v[0] = x2v[cb + tid];
            v[1] = x2v[cb + tid + 256];
            v[2] = x2v[cb + tid + 512];
            if (tid < 17) v[3] = x2v[cb + tid + 768];
        } else {
            #pragma unroll
            for (int j = 0; j < 4; ++j) {
                if (j < 3 || tid < 17) {
                    int gc = cb + tid + 256 * j;
                    u32x4 o;
                    #pragma unroll
                    for (int kk = 0; kk < 4; ++kk) {
                        int e0 = 8 * gc + 2 * kk;
                        int a0 = e0;     a0 = a0 < 0 ? 0 : (a0 >= XTOT ? XTOT - 1 : a0);
                        int a1 = e0 + 1; a1 = a1 < 0 ? 0 : (a1 >= XTOT ? XTOT - 1 : a1);
                        o[kk] = (u32)x2s[a0] | ((u32)x2s[a1] << 16);  // masked (w=0)
                    }
                    v[j] = o;
                }
            }
        }
    };
    auto st = [&](u32* wb) {   // linear layout, 4x ds_write_b128, conflict-free
        *reinterpret_cast<u32x4*>(&wb[4 * tid])         = v[0];
        *reinterpret_cast<u32x4*>(&wb[4 * (tid + 256)]) = v[1];
        *reinterpret_cast<u32x4*>(&wb[4 * (tid + 512)]) = v[2];
        if (tid < 17)
            *reinterpret_cast<u32x4*>(&wb[4 * (tid + 768)]) = v[3];
    };

    ld(0);   // batch-0 loads in flight across the MFMA phase

    // ---------- phase 2: P columns [32w,32w+32), kk-outer (A-frags shared) ----------
    const int wv_ = tid >> 6;
    const int l   = tid & 63;
    const int lr  = l & 15;
    const int kg  = l >> 4;

    f32x4 acc[4][2];
    #pragma unroll
    for (int mt = 0; mt < 4; ++mt) { acc[mt][0] = (f32x4)0.0f; acc[mt][1] = (f32x4)0.0f; }

    #pragma unroll
    for (int kk = 0; kk < 4; ++kk) {
        short8 aF[4];
        #pragma unroll
        for (int mt = 0; mt < 4; ++mt)
            aF[mt] = *reinterpret_cast<const short8*>(
                &hid_s[(16 * mt + lr) * HSTR + kk * 32 + kg * 8]);
        #pragma unroll
        for (int np = 0; np < 2; ++np) {
            const int bcol = 32 * wv_ + 16 * np + lr;
            short8 bH = *reinterpret_cast<const short8*>(wsH + bcol * CH + kk * 32 + kg * 8);
            short8 bL = *reinterpret_cast<const short8*>(wsL + bcol * CH + kk * 32 + kg * 8);
            #pragma unroll
            for (int mt = 0; mt < 4; ++mt) {
                acc[mt][np] = __builtin_amdgcn_mfma_f32_16x16x32_bf16(aF[mt], bH, acc[mt][np], 0, 0, 0);
                acc[mt][np] = __builtin_amdgcn_mfma_f32_16x16x32_bf16(aF[mt], bL, acc[mt][np], 0, 0, 0);
            }
        }
    }

    // ---------- phase 3: in-reg softmax + interval-bitmask mask -> wpack ----------
    {
        float wv[4][4];
        #pragma unroll
        for (int np = 0; np < 2; ++np) {
            const int chh = 32 * wv_ + 16 * np + lr;

            float mx = -1e30f;
            #pragma unroll
            for (int mt = 0; mt < 4; ++mt)
                #pragma unroll
                for (int r = 0; r < 4; ++r) {
                    int rr = 16 * mt + 4 * kg + r;
                    if (rr < R) mx = fmaxf(mx, acc[mt][np][r]);
                }
            mx = fmaxf(mx, __shfl_xor(mx, 16));
            mx = fmaxf(mx, __shfl_xor(mx, 32));

            float sm = 0.0f;
            #pragma unroll
            for (int mt = 0; mt < 4; ++mt)
                #pragma unroll
                for (int r = 0; r < 4; ++r) {
                    int rr = 16 * mt + 4 * kg + r;
                    float e = (rr < R) ? __expf(acc[mt][np][r] - mx) : 0.0f;
                    wv[mt][r] = e;
                    sm += e;
                }
            sm += __shfl_xor(sm, 16);
            sm += __shfl_xor(sm, 32);
            const float inv = 1.0f / sm;

            // validity bitmask over rr in [0,49)
            const int base = s * (R * CH) + chh * R;
            const int e2_0 = base & 127;
            const int jb   = base >> 7;
            const int j2_0 = jb % HH;
            const int rw   = 128 - e2_0;
            int j2p = j2_0 + 1; if (j2p == HH) j2p = 0;
            const bool rok1 = (j2_0 >= 3 - ii) && (j2_0 < 59 - ii);
            const bool rok2 = (j2p  >= 3 - ii) && (j2p  < 59 - ii);
            const int c1 = (3 - jj) - e2_0;
            const int c2 = (131 - jj) - e2_0;
            const int lo2 = c2 < rw ? c2 : rw;
            const int hi2 = c2 < rw ? rw : c2;
            u64 colm = ~(bitrange(0, c1) | bitrange(lo2, hi2));
            u64 rowm = (rok1 ? bitrange(0, rw) : 0ull) | (rok2 ? bitrange(rw, 49) : 0ull);
            u64 vm = (colm & rowm) >> (kg << 2);
            const u32 vlo = (u32)vm, vhi = (u32)(vm >> 32);

            #pragma unroll
            for (int mt = 0; mt < 4; ++mt)
                #pragma unroll
                for (int r = 0; r < 4; ++r) {
                    int rr = 16 * mt + 4 * kg + r;
                    if (rr < R) {
                        const int bp = 16 * mt + r;
                        bool ok = (((bp < 32 ? vlo : vhi) >> (bp & 31)) & 1u) != 0;
                        wv[mt][r] = ok ? wv[mt][r] * inv : 0.0f;
                    }
                }

            #pragma unroll
            for (int mt = 0; mt < 4; ++mt)
                #pragma unroll
                for (int jp = 0; jp < 2; ++jp) {
                    int j = 8 * mt + 2 * kg + jp;
                    if (j <= 24) {
                        u32 pk = (u32)(unsigned short)f2bf(wv[mt][2 * jp])
                               | ((u32)(unsigned short)f2bf(wv[mt][2 * jp + 1]) << 16);
                        wpack[j * CH + chh] = pk;
                    }
                }
        }
    }
    __syncthreads();          // hid dead (win0 overlay ok), wpack visible

    // ---------- per-thread weights: parity-aligned PACKED pairs qp[14] ----------
    u32 qp[14];
    {
        const int j0 = g ? 13 : 0;
        const int nj = g ? 12 : 13;
        u32 wr[14];
        #pragma unroll
        for (int i = 0; i < 13; ++i) wr[i] = (i < nj) ? wpack[(j0 + i) * CH + ch] : 0u;
        wr[13] = 0u;
        const int kw0 = g ? 26 : 0;
        const int par = (m2v + 49 * ch + kw0) & 1;
        u32 prev = 0u;
        #pragma unroll
        for (int i = 0; i < 14; ++i) {
            qp[i] = par ? ((wr[i] << 16) | (prev >> 16)) : wr[i];
            prev = wr[i];
        }
    }
#ifndef POATT_DOT2
    float qlo[14], qhi[14];
    #pragma unroll
    for (int i = 0; i < 14; ++i) {
        qlo[i] = bf2f_u(qp[i] & 0xffffu);
        qhi[i] = bf2f_u(qp[i] >> 16);
    }
#endif
    const int d0 = m3 + ((m2v + 49 * ch + (g ? 26 : 0)) >> 1);

    st(win0);                 // batch 0 -> win0 (hid dead; wpack reads done above)
    ld(1);                    // batch-1 loads in flight
    __syncthreads();          // win0 visible; all wpack reads complete

    // ---------- batch loop: double-buffered, ONE barrier per batch ----------
    #pragma unroll
    for (int b = 0; b < BS; ++b) {
        const u32* wb = (b & 1) ? win1 : win0;

        float acc2 = 0.0f;
        #pragma unroll
        for (int dd = 0; dd < 14; ++dd) {
            u32 wd = wb[d0 + dd];                // base + imm offset
#ifdef POATT_DOT2
            acc2 = __builtin_amdgcn_fdot2_f32_bf16(
                __builtin_bit_cast(bf16x2, wd),
                __builtin_bit_cast(bf16x2, qp[dd]),
                acc2, false);
#else
            acc2 = fmaf(__uint_as_float(wd << 16),         qlo[dd], acc2);
            acc2 = fmaf(__uint_as_float(wd & 0xffff0000u), qhi[dd], acc2);
#endif
        }

        if (b + 1 < BS) st((b & 1) ? win0 : win1);   // stage next batch into OTHER buf
        if (b + 2 < BS) ld(b + 2);                   // issue loads 2 batches ahead

        if (g) part_s[b & 1][ch] = acc2;
        __syncthreads();                              // next buf + part_s visible
        if (!g) trb[((size_t)b * NPOS + pos) * CH + ch] = acc2 + part_s[b & 1][ch];
    }
}

// ---------- transpose (b,pos,ch) -> (b,ch,pos) ----------
__global__ __launch_bounds__(256) void poatt_tr(
    const float* __restrict__ ws, float* __restrict__ out)
{
    __shared__ float t[64 * 129];
    const int blk = blockIdx.x;
    const int b   = blk / 49;
    const int p0  = (blk % 49) * 64;
    const int tid = threadIdx.x;

    const int chR = tid & 127, pR = tid >> 7;
    #pragma unroll
    for (int r = 0; r < 32; ++r) {
        int pl = pR + 2 * r;
        t[pl * 129 + chR] = ws[((size_t)b * NPOS + p0 + pl) * CH + chR];
    }
    __syncthreads();
    const int pW = tid & 63, chW0 = tid >> 6;
    #pragma unroll
    for (int c = 0; c < 32; ++c) {
        int chl = chW0 + 4 * c;
        out[((size_t)b * CH + chl) * NPOS + p0 + pW] = t[pW * 129 + chl];
    }
}

// ================= fallback: monolithic kernel (round-4 proven) =================
template<bool WS_W2, bool USE_WS>
__global__ __launch_bounds__(256, 4) void poatt_mono(
    const float* __restrict__ x,
    const float* __restrict__ W1, const float* __restrict__ b1,
    const float* __restrict__ W2,
    const short* __restrict__ wsH, const short* __restrict__ wsL,
    float* __restrict__ dst)
{
    __shared__ float rel_s[R][2];
    __shared__ __align__(16) char smem[2 * 64 * HSTR * 2];
    short* hidH = (short*)smem;
    short* hidL = hidH + 64 * HSTR;
    float* Pbuf = (float*)smem;

    const int pos = blockIdx.x;
    const int tid = threadIdx.x;
    const int ch  = tid & (CH - 1);
    const int g   = tid >> 7;

    const int q  = pos >> 6;
    const int ii = q / KS;
    const int jj = q % KS;

    if (tid < 2 * R) {
        const int e  = (tid >= R) ? 1 : 0;
        const int rr = tid - e * R;
        int F  = (pos * 2 + e) * R + rr;
        int ep = F & 1;
        int t  = F >> 1;
        int jp = t % HH; t /= HH;
        int a  = t % HH; t /= HH;
        int jc = t % KS;
        int ic = t / KS;
        int row = jp + ic - 3;
        int col = ep + jc - 3;
        float v = 0.0f;
        if (row >= 0 && row < HH && (col == 0 || col == 1)) {
            int f    = a * (HH * 2) + row * 2 + col;
            int cidx = f / NPOS;
            int p    = f - cidx * NPOS;
            int u    = (cidx == 0) ? (p / HH) : (p % HH);
            v = -3.0f + 6.0f * (float)u * (1.0f / 55.0f);
        }
        const float c0 = -3.0f + 6.0f * (float)(pos / HH) * (1.0f / 55.0f);
        const float c1 = -3.0f + 6.0f * (float)(pos % HH) * (1.0f / 55.0f);
        rel_s[rr][e] = v - ((e == 0) ? c0 : c1);
    }
    __syncthreads();

    {
        const float w10 = W1[ch];
        const float w11 = W1[CH + ch];
        const float bb  = b1[ch];
        for (int rr = g; rr < R; rr += 2) {
            float h = fmaf(rel_s[rr][0], w10, fmaf(rel_s[rr][1], w11, bb));
            h = fmaxf(h, 0.0f);
            short hi = f2bf(h);
            hidH[rr * HSTR + ch] = hi;
            hidL[rr * HSTR + ch] = f2bf(h - bf2f(hi));
        }
        for (int t = tid; t < 15 * HSTR; t += 256) {
            hidH[R * HSTR + t] = 0;
            hidL[R * HSTR + t] = 0;
        }
    }
    __syncthreads();

    {
        const int w  = tid >> 6;
        const int l  = tid & 63;
        const int lr = l & 15;
        const int kg = l >> 4;

        short8 aH[4], aL[4];
        const int abase = (16 * w + lr) * HSTR + kg * 8;
        #pragma unroll
        for (int kk = 0; kk < 4; ++kk) {
            aH[kk] = *reinterpret_cast<const short8*>(&hidH[abase + kk * 32]);
            aL[kk] = *reinterpret_cast<const short8*>(&hidL[abase + kk * 32]);
        }

        f32x4 acc[8];
        #pragma unroll
        for (int n = 0; n < 8; ++n) acc[n] = (f32x4)0.0f;

        #pragma unroll
        for (int n = 0; n < 8; ++n) {
            const int bcol = 16 * n + lr;
            #pragma unroll
            for (int kk = 0; kk < 4; ++kk) {
                short8 bH, bL;
                if (WS_W2) {
                    bH = *reinterpret_cast<const short8*>(wsH + bcol * CH + kk * 32 + kg * 8);
                    bL = *reinterpret_cast<const short8*>(wsL + bcol * CH + kk * 32 + kg * 8);
                } else {
                    #pragma unroll
                    for (int j = 0; j < 8; ++j) {
                        float ww = ((const float*)W2)[(kk * 32 + kg * 8 + j) * CH + bcol];
                        short hi = f2bf(ww);
                        bH[j] = hi;
                        bL[j] = f2bf(ww - bf2f(hi));
                    }
                }
                acc[n] = __builtin_amdgcn_mfma_f32_16x16x32_bf16(aL[kk], bH, acc[n], 0, 0, 0);
                acc[n] = __builtin_amdgcn_mfma_f32_16x16x32_bf16(aH[kk], bL, acc[n], 0, 0, 0);
                acc[n] = __builtin_amdgcn_mfma_f32_16x16x32_bf16(aH[kk], bH, acc[n], 0, 0, 0);
            }
        }
        __syncthreads();

        #pragma unroll
        for (int n = 0; n < 8; ++n) {
            #pragma unroll
            for (int r = 0; r < 4; ++r) {
                int rr = 16 * w + kg * 4 + r;
                if (rr < R) Pbuf[rr * PSTR + 16 * n + lr] = acc[n][r];
            }
        }
    }
    __syncthreads();

    if (tid < CH) {
        float p[R];
        #pragma unroll
        for (int rr = 0; rr < R; ++rr) p[rr] = Pbuf[rr * PSTR + tid];
        float mx = p[0];
        #pragma unroll
        for (int rr = 1; rr < R; ++rr) mx = fmaxf(mx, p[rr]);
        float s = 0.0f;
        #pragma unroll
        for (int rr = 0; rr < R; ++rr) { p[rr] = __expf(p[rr] - mx); s += p[rr]; }
        const float inv = 1.0f / s;
        const int wb0 = (pos & 63) * (R * CH);
        #pragma unroll
        for (int rr = 0; rr < R; ++rr) {
            int rem = wb0 + tid * R + rr;
            int e2  = rem & (CH - 1);
            int j2  = (rem >> 7) % HH;
            int row = j2 + ii - 3;
            int col = e2 + jj - 3;
            bool valid = (row >= 0) && (row < HH) && (col >= 0) && (col < CH);
            Pbuf[rr * PSTR + tid] = valid ? p[rr] * inv : 0.0f;
        }
    }
    __syncthreads();

    float p[R];
    #pragma unroll
    for (int rr = 0; rr < R; ++rr) p[rr] = Pbuf[rr * PSTR + ch];

    const int winbase = (pos & 63) * (R * CH) + (ii - 3) * CH + (jj - 3);
    const int base_t  = winbase + ch * R;

    #pragma unroll
    for (int bi = 0; bi < 4; ++bi) {
        const int b  = g * 4 + bi;
        const int ab = b * XSTR + base_t;
        const bool safe = (b > 0 || winbase >= 0) && (b < BS - 1 || winbase + R * CH <= XSTR);
        float acc = 0.0f;
        if (safe) {
            #pragma unroll
            for (int rr = 0; rr < R; ++rr) acc = fmaf(p[rr], x[ab + rr], acc);
        } else {
            #pragma unroll
            for (int rr = 0; rr < R; ++rr) {
                int a2 = ab + rr;
                a2 = a2 < 0 ? 0 : (a2 >= XTOT ? XTOT - 1 : a2);
                acc = fmaf(p[rr], x[a2], acc);
            }
        }
        if (USE_WS) dst[((size_t)b * NPOS + pos) * CH + ch] = acc;
        else        dst[((size_t)b * CH + ch) * NPOS + pos] = acc;
    }
}

extern "C" void kernel_launch(void* const* d_in, const int* in_sizes, int n_in,
                              void* d_out, int out_size, void* d_ws, size_t ws_size,
                              hipStream_t stream) {
    (void)in_sizes; (void)n_in; (void)out_size;
    const float* x  = (const float*)d_in[0];
    const float* W1 = (const float*)d_in[1];
    const float* b1 = (const float*)d_in[2];
    const float* W2 = (const float*)d_in[3];
    float* out = (float*)d_out;

    // ws layout: [W2T hi/lo 64KB][x2 bf16 6.125MB][trb 12.25MB]
    const size_t W2T_BYTES = 2u * CH * CH * sizeof(short);            //    65536
    const size_t X2_BYTES  = (size_t)XTOT * 2;                        //  6422528
    const size_t TRB_BYTES = (size_t)BS * NPOS * CH * sizeof(float);  // 12845056
    const size_t FULL = W2T_BYTES + X2_BYTES + TRB_BYTES;             // 19333120

    short* wsH = (short*)d_ws;
    short* wsL = wsH + CH * CH;

    if (ws_size >= FULL) {
        u32*   x2  = (u32*)((char*)d_ws + W2T_BYTES);
        float* trb = (float*)((char*)d_ws + W2T_BYTES + X2_BYTES);

        poatt_pc<<<dim3(XTOT / (256 * 8)), dim3(256), 0, stream>>>(x, W2, x2, wsH, wsL);
        poatt_fused<<<dim3(NPOS), dim3(256), 0, stream>>>(x2, W1, b1, wsH, wsL, trb);
        poatt_tr<<<dim3(BS * 49), dim3(256), 0, stream>>>(trb, out);
    } else if (ws_size >= W2T_BYTES + TRB_BYTES) {
        float* trb = (float*)((char*)d_ws + W2T_BYTES);
        poatt_prep<<<dim3(64), dim3(256), 0, stream>>>(W2, wsH, wsL);
        poatt_mono<true, true><<<dim3(NPOS), dim3(256), 0, stream>>>(
            x, W1, b1, W2, wsH, wsL, trb);
        poatt_tr<<<dim3(BS * 49), dim3(256), 0, stream>>>(trb, out);
    } else if (ws_size >= W2T_BYTES) {
        poatt_prep<<<dim3(64), dim3(256), 0, stream>>>(W2, wsH, wsL);
        poatt_mono<true, false><<<dim3(NPOS), dim3(256), 0, stream>>>(
            x, W1, b1, W2, wsH, wsL, out);
    } else {
        poatt_mono<false, false><<<dim3(NPOS), dim3(256), 0, stream>>>(
            x, W1, b1, W2, nullptr, nullptr, out);
    }
}

// Round 14
// 69.591 us; speedup vs baseline: 1.2519x; 1.0003x over previous
//
#include <hip/hip_runtime.h>

#define CH   128
#define KS   7
#define R    49
#define HH   56
#define NPOS 3136
#define BS   8
#define XSTR 401408
#define XTOT (BS*XSTR)

typedef short short8 __attribute__((ext_vector_type(8)));
typedef float f32x4  __attribute__((ext_vector_type(4)));
typedef unsigned int u32;
typedef unsigned long long u64;
typedef u32 u32x4 __attribute__((ext_vector_type(4)));
typedef __bf16 bf16x2 __attribute__((ext_vector_type(2)));

#if defined(__has_builtin)
#if __has_builtin(__builtin_amdgcn_fdot2_f32_bf16)
#define POATT_DOT2 1
#endif
#endif

__device__ __forceinline__ short f2bf(float f) {            // RNE fp32->bf16
    unsigned u = __float_as_uint(f);
    u += 0x7fffu + ((u >> 16) & 1u);
    return (short)(u >> 16);
}
__device__ __forceinline__ float bf2f(short s) {
    return __uint_as_float(((unsigned)(unsigned short)s) << 16);
}
__device__ __forceinline__ float bf2f_u(u32 lo16) {
    return __uint_as_float(lo16 << 16);
}
__device__ __forceinline__ u64 bitrange(int a, int b) {     // bits [a,b) clamped to [0,49]
    a = a < 0 ? 0 : (a > 49 ? 49 : a);
    b = b < 0 ? 0 : (b > 49 ? 49 : b);
    if (b <= a) return 0ull;
    return (1ull << b) - (1ull << a);
}

#define HSTR 136            // hid LDS row stride (bf16 elems)
#define PSTR 132            // P LDS row stride (fp32) - mono fallback only
#define NWIN 3140           // win dwords (785 u32x4 chunks)

// ---------- prep (fallback path only) ----------
__global__ __launch_bounds__(256) void poatt_prep(
    const float* __restrict__ W2, short* __restrict__ wsH, short* __restrict__ wsL)
{
    int t = blockIdx.x * 256 + threadIdx.x;
    int k = t >> 7, ch = t & 127;
    float w = W2[k * CH + ch];
    short hi = f2bf(w);
    wsH[ch * CH + k] = hi;
    wsL[ch * CH + k] = f2bf(w - bf2f(hi));
}

// ---------- combined: cvt x->bf16 pairs + W2 prep (first 64 blocks) ----------
__global__ __launch_bounds__(256) void poatt_pc(
    const float* __restrict__ x, const float* __restrict__ W2,
    u32* __restrict__ x2, short* __restrict__ wsH, short* __restrict__ wsL)
{
    int t = blockIdx.x * 256 + threadIdx.x;      // grid 1568
    const float4* xv = reinterpret_cast<const float4*>(x);
    float4 a = xv[2 * t], b = xv[2 * t + 1];
    u32x4 o;
    o[0] = (u32)(unsigned short)f2bf(a.x) | ((u32)(unsigned short)f2bf(a.y) << 16);
    o[1] = (u32)(unsigned short)f2bf(a.z) | ((u32)(unsigned short)f2bf(a.w) << 16);
    o[2] = (u32)(unsigned short)f2bf(b.x) | ((u32)(unsigned short)f2bf(b.y) << 16);
    o[3] = (u32)(unsigned short)f2bf(b.z) | ((u32)(unsigned short)f2bf(b.w) << 16);
    reinterpret_cast<u32x4*>(x2)[t] = o;

    if (t < CH * CH) {
        int k = t >> 7, ch = t & 127;
        float w = W2[k * CH + ch];
        short hi = f2bf(w);
        wsH[ch * CH + k] = hi;
        wsL[ch * CH + k] = f2bf(w - bf2f(hi));
    }
}

// ---------- fused: weights (MFMA + in-reg softmax) + 8-batch dbuf apply ----------
__global__ __launch_bounds__(256, 4) void poatt_fused(
    const u32* __restrict__ x2,
    const float* __restrict__ W1, const float* __restrict__ b1,
    const short* __restrict__ wsH, const short* __restrict__ wsL,
    float* __restrict__ trb)         // (b,pos,ch)
{
    __shared__ float rel_s[R][2];
    __shared__ float part_s[2][CH];
    __shared__ u32 wpack[25 * CH];                    // 12800 B: weights, then win1
    __shared__ __align__(16) char smem[64 * HSTR * 2];// 17408 B: hid, then win0
    short* hid_s = (short*)smem;
    u32*   win0  = (u32*)smem;                        // overlays hid
    u32*   win1  = wpack;                             // overlays wpack

    const int pos = blockIdx.x;                       // natural: XCD = s mod 8
    const int tid = threadIdx.x;
    const int ch  = tid & (CH - 1);
    const int g   = tid >> 7;

    const int q  = pos >> 6;
    const int s  = pos & 63;
    const int ii = q / KS;
    const int jj = q % KS;

    // ---------- phase 0: rel ----------
    if (tid < 2 * R) {
        const int e  = (tid >= R) ? 1 : 0;
        const int rr = tid - e * R;
        int F  = (pos * 2 + e) * R + rr;
        int ep = F & 1;
        int t  = F >> 1;
        int jp = t % HH; t /= HH;
        int a  = t % HH; t /= HH;
        int jc = t % KS;
        int ic = t / KS;
        int row = jp + ic - 3;
        int col = ep + jc - 3;
        float v = 0.0f;
        if (row >= 0 && row < HH && (col == 0 || col == 1)) {
            int f    = a * (HH * 2) + row * 2 + col;
            int cidx = f / NPOS;
            int p    = f - cidx * NPOS;
            int u    = (cidx == 0) ? (p / HH) : (p % HH);
            v = -3.0f + 6.0f * (float)u * (1.0f / 55.0f);
        }
        const float c0 = -3.0f + 6.0f * (float)(pos / HH) * (1.0f / 55.0f);
        const float c1 = -3.0f + 6.0f * (float)(pos % HH) * (1.0f / 55.0f);
        rel_s[rr][e] = v - ((e == 0) ? c0 : c1);
    }
    __syncthreads();

    // ---------- phase 1: hid = relu(rel@W1+b1) -> bf16 LDS ----------
    {
        const float w10 = W1[ch];
        const float w11 = W1[CH + ch];
        const float bb  = b1[ch];
        for (int rr = g; rr < R; rr += 2) {
            float h = fmaf(rel_s[rr][0], w10, fmaf(rel_s[rr][1], w11, bb));
            hid_s[rr * HSTR + ch] = f2bf(fmaxf(h, 0.0f));
        }
        for (int t = tid; t < 15 * HSTR; t += 256) hid_s[R * HSTR + t] = 0;
    }
    __syncthreads();

    // ---------- window geometry ----------
    const int winbase = s * (R * CH) + (ii - 3) * CH + (jj - 3);
    const int m2v = winbase & 1;
    const int hw  = winbase >> 1;
    const int m3  = hw & 3;
    const int cw0 = (hw - m3) >> 2;               // u32x4 chunk base (batch plane)
    const u32x4* x2v = reinterpret_cast<const u32x4*>(x2);
    const unsigned short* x2s = reinterpret_cast<const unsigned short*>(x2);

    u32x4 v[4];
    auto ld = [&](int b) {
        const int cb = b * (XSTR >> 3) + cw0;
        const bool safe = (b > 0 || winbase >= 8) && (b < BS - 1 || winbase + 6280 <= XSTR);
        if (safe) {
            v[0] = x2v[cb + tid];
            v[1] = x2v[cb + tid + 256];
            v[2] = x2v[cb + tid + 512];
            if (tid < 17) v[3] = x2v[cb + tid + 768];
        } else {
            #pragma unroll
            for (int j = 0; j < 4; ++j) {
                if (j < 3 || tid < 17) {
                    int gc = cb + tid + 256 * j;
                    u32x4 o;
                    #pragma unroll
                    for (int kk = 0; kk < 4; ++kk) {
                        int e0 = 8 * gc + 2 * kk;
                        int a0 = e0;     a0 = a0 < 0 ? 0 : (a0 >= XTOT ? XTOT - 1 : a0);
                        int a1 = e0 + 1; a1 = a1 < 0 ? 0 : (a1 >= XTOT ? XTOT - 1 : a1);
                        o[kk] = (u32)x2s[a0] | ((u32)x2s[a1] << 16);  // masked (w=0)
                    }
                    v[j] = o;
                }
            }
        }
    };
    auto st = [&](u32* wb) {   // linear layout, 4x ds_write_b128, conflict-free
        *reinterpret_cast<u32x4*>(&wb[4 * tid])         = v[0];
        *reinterpret_cast<u32x4*>(&wb[4 * (tid + 256)]) = v[1];
        *reinterpret_cast<u32x4*>(&wb[4 * (tid + 512)]) = v[2];
        if (tid < 17)
            *reinterpret_cast<u32x4*>(&wb[4 * (tid + 768)]) = v[3];
    };

    ld(0);   // batch-0 loads in flight across the MFMA phase

    // ---------- phase 2: P columns [32w,32w+32), kk-outer (A-frags shared) ----------
    const int wv_ = tid >> 6;
    const int l   = tid & 63;
    const int lr  = l & 15;
    const int kg  = l >> 4;

    f32x4 acc[4][2];
    #pragma unroll
    for (int mt = 0; mt < 4; ++mt) { acc[mt][0] = (f32x4)0.0f; acc[mt][1] = (f32x4)0.0f; }

    #pragma unroll
    for (int kk = 0; kk < 4; ++kk) {
        short8 aF[4];
        #pragma unroll
        for (int mt = 0; mt < 4; ++mt)
            aF[mt] = *reinterpret_cast<const short8*>(
                &hid_s[(16 * mt + lr) * HSTR + kk * 32 + kg * 8]);
        #pragma unroll
        for (int np = 0; np < 2; ++np) {
            const int bcol = 32 * wv_ + 16 * np + lr;
            short8 bH = *reinterpret_cast<const short8*>(wsH + bcol * CH + kk * 32 + kg * 8);
            short8 bL = *reinterpret_cast<const short8*>(wsL + bcol * CH + kk * 32 + kg * 8);
            #pragma unroll
            for (int mt = 0; mt < 4; ++mt) {
                acc[mt][np] = __builtin_amdgcn_mfma_f32_16x16x32_bf16(aF[mt], bH, acc[mt][np], 0, 0, 0);
                acc[mt][np] = __builtin_amdgcn_mfma_f32_16x16x32_bf16(aF[mt], bL, acc[mt][np], 0, 0, 0);
            }
        }
    }

    // ---------- phase 3: in-reg softmax + interval-bitmask mask -> wpack ----------
    {
        float wv[4][4];
        #pragma unroll
        for (int np = 0; np < 2; ++np) {
            const int chh = 32 * wv_ + 16 * np + lr;

            float mx = -1e30f;
            #pragma unroll
            for (int mt = 0; mt < 4; ++mt)
                #pragma unroll
                for (int r = 0; r < 4; ++r) {
                    int rr = 16 * mt + 4 * kg + r;
                    if (rr < R) mx = fmaxf(mx, acc[mt][np][r]);
                }
            mx = fmaxf(mx, __shfl_xor(mx, 16));
            mx = fmaxf(mx, __shfl_xor(mx, 32));

            float sm = 0.0f;
            #pragma unroll
            for (int mt = 0; mt < 4; ++mt)
                #pragma unroll
                for (int r = 0; r < 4; ++r) {
                    int rr = 16 * mt + 4 * kg + r;
                    float e = (rr < R) ? __expf(acc[mt][np][r] - mx) : 0.0f;
                    wv[mt][r] = e;
                    sm += e;
                }
            sm += __shfl_xor(sm, 16);
            sm += __shfl_xor(sm, 32);
            const float inv = 1.0f / sm;

            // validity bitmask over rr in [0,49)
            const int base = s * (R * CH) + chh * R;
            const int e2_0 = base & 127;
            const int jb   = base >> 7;
            const int j2_0 = jb % HH;
            const int rw   = 128 - e2_0;
            int j2p = j2_0 + 1; if (j2p == HH) j2p = 0;
            const bool rok1 = (j2_0 >= 3 - ii) && (j2_0 < 59 - ii);
            const bool rok2 = (j2p  >= 3 - ii) && (j2p  < 59 - ii);
            const int c1 = (3 - jj) - e2_0;
            const int c2 = (131 - jj) - e2_0;
            const int lo2 = c2 < rw ? c2 : rw;
            const int hi2 = c2 < rw ? rw : c2;
            u64 colm = ~(bitrange(0, c1) | bitrange(lo2, hi2));
            u64 rowm = (rok1 ? bitrange(0, rw) : 0ull) | (rok2 ? bitrange(rw, 49) : 0ull);
            u64 vm = (colm & rowm) >> (kg << 2);
            const u32 vlo = (u32)vm, vhi = (u32)(vm >> 32);

            #pragma unroll
            for (int mt = 0; mt < 4; ++mt)
                #pragma unroll
                for (int r = 0; r < 4; ++r) {
                    int rr = 16 * mt + 4 * kg + r;
                    if (rr < R) {
                        const int bp = 16 * mt + r;
                        bool ok = (((bp < 32 ? vlo : vhi) >> (bp & 31)) & 1u) != 0;
                        wv[mt][r] = ok ? wv[mt][r] * inv : 0.0f;
                    }
                }

            #pragma unroll
            for (int mt = 0; mt < 4; ++mt)
                #pragma unroll
                for (int jp = 0; jp < 2; ++jp) {
                    int j = 8 * mt + 2 * kg + jp;
                    if (j <= 24) {
                        u32 pk = (u32)(unsigned short)f2bf(wv[mt][2 * jp])
                               | ((u32)(unsigned short)f2bf(wv[mt][2 * jp + 1]) << 16);
                        wpack[j * CH + chh] = pk;
                    }
                }
        }
    }
    __syncthreads();          // hid dead (win0 overlay ok), wpack visible

    // ---------- per-thread weights: parity-aligned PACKED pairs qp[14] ----------
    u32 qp[14];
    {
        const int j0 = g ? 13 : 0;
        const int nj = g ? 12 : 13;
        u32 wr[14];
        #pragma unroll
        for (int i = 0; i < 13; ++i) wr[i] = (i < nj) ? wpack[(j0 + i) * CH + ch] : 0u;
        wr[13] = 0u;
        const int kw0 = g ? 26 : 0;
        const int par = (m2v + 49 * ch + kw0) & 1;
        u32 prev = 0u;
        #pragma unroll
        for (int i = 0; i < 14; ++i) {
            qp[i] = par ? ((wr[i] << 16) | (prev >> 16)) : wr[i];
            prev = wr[i];
        }
    }
#ifndef POATT_DOT2
    float qlo[14], qhi[14];
    #pragma unroll
    for (int i = 0; i < 14; ++i) {
        qlo[i] = bf2f_u(qp[i] & 0xffffu);
        qhi[i] = bf2f_u(qp[i] >> 16);
    }
#endif
    const int d0 = m3 + ((m2v + 49 * ch + (g ? 26 : 0)) >> 1);

    st(win0);                 // batch 0 -> win0 (hid dead; wpack reads done above)
    ld(1);                    // batch-1 loads in flight
    __syncthreads();          // win0 visible; all wpack reads complete

    // ---------- batch loop: double-buffered, ONE barrier per batch ----------
    #pragma unroll
    for (int b = 0; b < BS; ++b) {
        const u32* wb = (b & 1) ? win1 : win0;

        float acc2 = 0.0f;
        #pragma unroll
        for (int dd = 0; dd < 14; ++dd) {
            u32 wd = wb[d0 + dd];                // base + imm offset
#ifdef POATT_DOT2
            acc2 = __builtin_amdgcn_fdot2_f32_bf16(
                __builtin_bit_cast(bf16x2, wd),
                __builtin_bit_cast(bf16x2, qp[dd]),
                acc2, false);
#else
            acc2 = fmaf(__uint_as_float(wd << 16),         qlo[dd], acc2);
            acc2 = fmaf(__uint_as_float(wd & 0xffff0000u), qhi[dd], acc2);
#endif
        }

        if (b + 1 < BS) st((b & 1) ? win0 : win1);   // stage next batch into OTHER buf
        if (b + 2 < BS) ld(b + 2);                   // issue loads 2 batches ahead

        if (g) part_s[b & 1][ch] = acc2;
        __syncthreads();                              // next buf + part_s visible
        if (!g) trb[((size_t)b * NPOS + pos) * CH + ch] = acc2 + part_s[b & 1][ch];
    }
}

// ---------- transpose (b,pos,ch) -> (b,ch,pos) ----------
__global__ __launch_bounds__(256) void poatt_tr(
    const float* __restrict__ ws, float* __restrict__ out)
{
    __shared__ float t[64 * 129];
    const int blk = blockIdx.x;
    const int b   = blk / 49;
    const int p0  = (blk % 49) * 64;
    const int tid = threadIdx.x;

    const int chR = tid & 127, pR = tid >> 7;
    #pragma unroll
    for (int r = 0; r < 32; ++r) {
        int pl = pR + 2 * r;
        t[pl * 129 + chR] = ws[((size_t)b * NPOS + p0 + pl) * CH + chR];
    }
    __syncthreads();
    const int pW = tid & 63, chW0 = tid >> 6;
    #pragma unroll
    for (int c = 0; c < 32; ++c) {
        int chl = chW0 + 4 * c;
        out[((size_t)b * CH + chl) * NPOS + p0 + pW] = t[pW * 129 + chl];
    }
}

// ================= fallback: monolithic kernel (round-4 proven) =================
template<bool WS_W2, bool USE_WS>
__global__ __launch_bounds__(256, 4) void poatt_mono(
    const float* __restrict__ x,
    const float* __restrict__ W1, const float* __restrict__ b1,
    const float* __restrict__ W2,
    const short* __restrict__ wsH, const short* __restrict__ wsL,
    float* __restrict__ dst)
{
    __shared__ float rel_s[R][2];
    __shared__ __align__(16) char smem[2 * 64 * HSTR * 2];
    short* hidH = (short*)smem;
    short* hidL = hidH + 64 * HSTR;
    float* Pbuf = (float*)smem;

    const int pos = blockIdx.x;
    const int tid = threadIdx.x;
    const int ch  = tid & (CH - 1);
    const int g   = tid >> 7;

    const int q  = pos >> 6;
    const int ii = q / KS;
    const int jj = q % KS;

    if (tid < 2 * R) {
        const int e  = (tid >= R) ? 1 : 0;
        const int rr = tid - e * R;
        int F  = (pos * 2 + e) * R + rr;
        int ep = F & 1;
        int t  = F >> 1;
        int jp = t % HH; t /= HH;
        int a  = t % HH; t /= HH;
        int jc = t % KS;
        int ic = t / KS;
        int row = jp + ic - 3;
        int col = ep + jc - 3;
        float v = 0.0f;
        if (row >= 0 && row < HH && (col == 0 || col == 1)) {
            int f    = a * (HH * 2) + row * 2 + col;
            int cidx = f / NPOS;
            int p    = f - cidx * NPOS;
            int u    = (cidx == 0) ? (p / HH) : (p % HH);
            v = -3.0f + 6.0f * (float)u * (1.0f / 55.0f);
        }
        const float c0 = -3.0f + 6.0f * (float)(pos / HH) * (1.0f / 55.0f);
        const float c1 = -3.0f + 6.0f * (float)(pos % HH) * (1.0f / 55.0f);
        rel_s[rr][e] = v - ((e == 0) ? c0 : c1);
    }
    __syncthreads();

    {
        const float w10 = W1[ch];
        const float w11 = W1[CH + ch];
        const float bb  = b1[ch];
        for (int rr = g; rr < R; rr += 2) {
            float h = fmaf(rel_s[rr][0], w10, fmaf(rel_s[rr][1], w11, bb));
            h = fmaxf(h, 0.0f);
            short hi = f2bf(h);
            hidH[rr * HSTR + ch] = hi;
            hidL[rr * HSTR + ch] = f2bf(h - bf2f(hi));
        }
        for (int t = tid; t < 15 * HSTR; t += 256) {
            hidH[R * HSTR + t] = 0;
            hidL[R * HSTR + t] = 0;
        }
    }
    __syncthreads();

    {
        const int w  = tid >> 6;
        const int l  = tid & 63;
        const int lr = l & 15;
        const int kg = l >> 4;

        short8 aH[4], aL[4];
        const int abase = (16 * w + lr) * HSTR + kg * 8;
        #pragma unroll
        for (int kk = 0; kk < 4; ++kk) {
            aH[kk] = *reinterpret_cast<const short8*>(&hidH[abase + kk * 32]);
            aL[kk] = *reinterpret_cast<const short8*>(&hidL[abase + kk * 32]);
        }

        f32x4 acc[8];
        #pragma unroll
        for (int n = 0; n < 8; ++n) acc[n] = (f32x4)0.0f;

        #pragma unroll
        for (int n = 0; n < 8; ++n) {
            const int bcol = 16 * n + lr;
            #pragma unroll
            for (int kk = 0; kk < 4; ++kk) {
                short8 bH, bL;
                if (WS_W2) {
                    bH = *reinterpret_cast<const short8*>(wsH + bcol * CH + kk * 32 + kg * 8);
                    bL = *reinterpret_cast<const short8*>(wsL + bcol * CH + kk * 32 + kg * 8);
                } else {
                    #pragma unroll
                    for (int j = 0; j < 8; ++j) {
                        float ww = ((const float*)W2)[(kk * 32 + kg * 8 + j) * CH + bcol];
                        short hi = f2bf(ww);
                        bH[j] = hi;
                        bL[j] = f2bf(ww - bf2f(hi));
                    }
                }
                acc[n] = __builtin_amdgcn_mfma_f32_16x16x32_bf16(aL[kk], bH, acc[n], 0, 0, 0);
                acc[n] = __builtin_amdgcn_mfma_f32_16x16x32_bf16(aH[kk], bL, acc[n], 0, 0, 0);
                acc[n] = __builtin_amdgcn_mfma_f32_16x16x32_bf16(aH[kk], bH, acc[n], 0, 0, 0);
            }
        }
        __syncthreads();

        #pragma unroll
        for (int n = 0; n < 8; ++n) {
            #pragma unroll
            for (int r = 0; r < 4; ++r) {
                int rr = 16 * w + kg * 4 + r;
                if (rr < R) Pbuf[rr * PSTR + 16 * n + lr] = acc[n][r];
            }
        }
    }
    __syncthreads();

    if (tid < CH) {
        float p[R];
        #pragma unroll
        for (int rr = 0; rr < R; ++rr) p[rr] = Pbuf[rr * PSTR + tid];
        float mx = p[0];
        #pragma unroll
        for (int rr = 1; rr < R; ++rr) mx = fmaxf(mx, p[rr]);
        float s = 0.0f;
        #pragma unroll
        for (int rr = 0; rr < R; ++rr) { p[rr] = __expf(p[rr] - mx); s += p[rr]; }
        const float inv = 1.0f / s;
        const int wb0 = (pos & 63) * (R * CH);
        #pragma unroll
        for (int rr = 0; rr < R; ++rr) {
            int rem = wb0 + tid * R + rr;
            int e2  = rem & (CH - 1);
            int j2  = (rem >> 7) % HH;
            int row = j2 + ii - 3;
            int col = e2 + jj - 3;
            bool valid = (row >= 0) && (row < HH) && (col >= 0) && (col < CH);
            Pbuf[rr * PSTR + tid] = valid ? p[rr] * inv : 0.0f;
        }
    }
    __syncthreads();

    float p[R];
    #pragma unroll
    for (int rr = 0; rr < R; ++rr) p[rr] = Pbuf[rr * PSTR + ch];

    const int winbase = (pos & 63) * (R * CH) + (ii - 3) * CH + (jj - 3);
    const int base_t  = winbase + ch * R;

    #pragma unroll
    for (int bi = 0; bi < 4; ++bi) {
        const int b  = g * 4 + bi;
        const int ab = b * XSTR + base_t;
        const bool safe = (b > 0 || winbase >= 0) && (b < BS - 1 || winbase + R * CH <= XSTR);
        float acc = 0.0f;
        if (safe) {
            #pragma unroll
            for (int rr = 0; rr < R; ++rr) acc = fmaf(p[rr], x[ab + rr], acc);
        } else {
            #pragma unroll
            for (int rr = 0; rr < R; ++rr) {
                int a2 = ab + rr;
                a2 = a2 < 0 ? 0 : (a2 >= XTOT ? XTOT - 1 : a2);
                acc = fmaf(p[rr], x[a2], acc);
            }
        }
        if (USE_WS) dst[((size_t)b * NPOS + pos) * CH + ch] = acc;
        else        dst[((size_t)b * CH + ch) * NPOS + pos] = acc;
    }
}

extern "C" void kernel_launch(void* const* d_in, const int* in_sizes, int n_in,
                              void* d_out, int out_size, void* d_ws, size_t ws_size,
                              hipStream_t stream) {
    (void)in_sizes; (void)n_in; (void)out_size;
    const float* x  = (const float*)d_in[0];
    const float* W1 = (const float*)d_in[1];
    const float* b1 = (const float*)d_in[2];
    const float* W2 = (const float*)d_in[3];
    float* out = (float*)d_out;

    // ws layout: [W2T hi/lo 64KB][x2 bf16 6.125MB][trb 12.25MB]
    const size_t W2T_BYTES = 2u * CH * CH * sizeof(short);            //    65536
    const size_t X2_BYTES  = (size_t)XTOT * 2;                        //  6422528
    const size_t TRB_BYTES = (size_t)BS * NPOS * CH * sizeof(float);  // 12845056
    const size_t FULL = W2T_BYTES + X2_BYTES + TRB_BYTES;             // 19333120

    short* wsH = (short*)d_ws;
    short* wsL = wsH + CH * CH;

    if (ws_size >= FULL) {
        u32*   x2  = (u32*)((char*)d_ws + W2T_BYTES);
        float* trb = (float*)((char*)d_ws + W2T_BYTES + X2_BYTES);

        poatt_pc<<<dim3(XTOT / (256 * 8)), dim3(256), 0, stream>>>(x, W2, x2, wsH, wsL);
        poatt_fused<<<dim3(NPOS), dim3(256), 0, stream>>>(x2, W1, b1, wsH, wsL, trb);
        poatt_tr<<<dim3(BS * 49), dim3(256), 0, stream>>>(trb, out);
    } else if (ws_size >= W2T_BYTES + TRB_BYTES) {
        float* trb = (float*)((char*)d_ws + W2T_BYTES);
        poatt_prep<<<dim3(64), dim3(256), 0, stream>>>(W2, wsH, wsL);
        poatt_mono<true, true><<<dim3(NPOS), dim3(256), 0, stream>>>(
            x, W1, b1, W2, wsH, wsL, trb);
        poatt_tr<<<dim3(BS * 49), dim3(256), 0, stream>>>(trb, out);
    } else if (ws_size >= W2T_BYTES) {
        poatt_prep<<<dim3(64), dim3(256), 0, stream>>>(W2, wsH, wsL);
        poatt_mono<true, false><<<dim3(NPOS), dim3(256), 0, stream>>>(
            x, W1, b1, W2, wsH, wsL, out);
    } else {
        poatt_mono<false, false><<<dim3(NPOS), dim3(256), 0, stream>>>(
            x, W1, b1, W2, nullptr, nullptr, out);
    }
}

// Round 15
// 69.132 us; speedup vs baseline: 1.2603x; 1.0066x over previous
//
#include <hip/hip_runtime.h>

#define CH   128
#define KS   7
#define R    49
#define HH   56
#define NPOS 3136
#define BS   8
#define XSTR 401408
#define XTOT (BS*XSTR)

typedef short short8 __attribute__((ext_vector_type(8)));
typedef float f32x4  __attribute__((ext_vector_type(4)));
typedef unsigned int u32;
typedef unsigned long long u64;
typedef u32 u32x4 __attribute__((ext_vector_type(4)));
typedef __bf16 bf16x2 __attribute__((ext_vector_type(2)));

#if defined(__has_builtin)
#if __has_builtin(__builtin_amdgcn_fdot2_f32_bf16)
#define POATT_DOT2 1
#endif
#endif

__device__ __forceinline__ short f2bf(float f) {            // RNE fp32->bf16
    unsigned u = __float_as_uint(f);
    u += 0x7fffu + ((u >> 16) & 1u);
    return (short)(u >> 16);
}
__device__ __forceinline__ float bf2f(short s) {
    return __uint_as_float(((unsigned)(unsigned short)s) << 16);
}
__device__ __forceinline__ float bf2f_u(u32 lo16) {
    return __uint_as_float(lo16 << 16);
}
__device__ __forceinline__ u64 bitrange(int a, int b) {     // bits [a,b) clamped to [0,49]
    a = a < 0 ? 0 : (a > 49 ? 49 : a);
    b = b < 0 ? 0 : (b > 49 ? 49 : b);
    if (b <= a) return 0ull;
    return (1ull << b) - (1ull << a);
}

#define HSTR 136            // hid LDS row stride (bf16 elems)
#define PSTR 132            // P LDS row stride (fp32) - mono fallback only
#define NWIN 3140           // win dwords (785 u32x4 chunks)

// ---------- prep (fallback path only) ----------
__global__ __launch_bounds__(256) void poatt_prep(
    const float* __restrict__ W2, short* __restrict__ wsH, short* __restrict__ wsL)
{
    int t = blockIdx.x * 256 + threadIdx.x;
    int k = t >> 7, ch = t & 127;
    float w = W2[k * CH + ch];
    short hi = f2bf(w);
    wsH[ch * CH + k] = hi;
    wsL[ch * CH + k] = f2bf(w - bf2f(hi));
}

// ---------- combined: cvt x->bf16 pairs + W2 prep (first 64 blocks) ----------
__global__ __launch_bounds__(256) void poatt_pc(
    const float* __restrict__ x, const float* __restrict__ W2,
    u32* __restrict__ x2, short* __restrict__ wsH, short* __restrict__ wsL)
{
    int t = blockIdx.x * 256 + threadIdx.x;      // grid 1568
    const float4* xv = reinterpret_cast<const float4*>(x);
    float4 a = xv[2 * t], b = xv[2 * t + 1];
    u32x4 o;
    o[0] = (u32)(unsigned short)f2bf(a.x) | ((u32)(unsigned short)f2bf(a.y) << 16);
    o[1] = (u32)(unsigned short)f2bf(a.z) | ((u32)(unsigned short)f2bf(a.w) << 16);
    o[2] = (u32)(unsigned short)f2bf(b.x) | ((u32)(unsigned short)f2bf(b.y) << 16);
    o[3] = (u32)(unsigned short)f2bf(b.z) | ((u32)(unsigned short)f2bf(b.w) << 16);
    reinterpret_cast<u32x4*>(x2)[t] = o;

    if (t < CH * CH) {
        int k = t >> 7, ch = t & 127;
        float w = W2[k * CH + ch];
        short hi = f2bf(w);
        wsH[ch * CH + k] = hi;
        wsL[ch * CH + k] = f2bf(w - bf2f(hi));
    }
}

// ---------- fused: weights (MFMA + in-reg softmax) + 8-batch dbuf apply ----------
__global__ __launch_bounds__(256, 4) void poatt_fused(
    const u32* __restrict__ x2,
    const float* __restrict__ W1, const float* __restrict__ b1,
    const short* __restrict__ wsH, const short* __restrict__ wsL,
    float* __restrict__ trb)         // (b,pos,ch)
{
    __shared__ float rel_s[R][2];
    __shared__ float part_s[2][CH];
    __shared__ u32 wpack[25 * CH];                    // 12800 B: weights, then win1
    __shared__ __align__(16) char smem[64 * HSTR * 2];// 17408 B: hid, then win0
    short* hid_s = (short*)smem;
    u32*   win0  = (u32*)smem;                        // overlays hid
    u32*   win1  = wpack;                             // overlays wpack

    const int pos = blockIdx.x;                       // natural: XCD = s mod 8
    const int tid = threadIdx.x;
    const int ch  = tid & (CH - 1);
    const int g   = tid >> 7;

    const int q  = pos >> 6;
    const int s  = pos & 63;
    const int ii = q / KS;
    const int jj = q % KS;

    // ---------- phase 0: rel ----------
    if (tid < 2 * R) {
        const int e  = (tid >= R) ? 1 : 0;
        const int rr = tid - e * R;
        int F  = (pos * 2 + e) * R + rr;
        int ep = F & 1;
        int t  = F >> 1;
        int jp = t % HH; t /= HH;
        int a  = t % HH; t /= HH;
        int jc = t % KS;
        int ic = t / KS;
        int row = jp + ic - 3;
        int col = ep + jc - 3;
        float v = 0.0f;
        if (row >= 0 && row < HH && (col == 0 || col == 1)) {
            int f    = a * (HH * 2) + row * 2 + col;
            int cidx = f / NPOS;
            int p    = f - cidx * NPOS;
            int u    = (cidx == 0) ? (p / HH) : (p % HH);
            v = -3.0f + 6.0f * (float)u * (1.0f / 55.0f);
        }
        const float c0 = -3.0f + 6.0f * (float)(pos / HH) * (1.0f / 55.0f);
        const float c1 = -3.0f + 6.0f * (float)(pos % HH) * (1.0f / 55.0f);
        rel_s[rr][e] = v - ((e == 0) ? c0 : c1);
    }
    __syncthreads();

    // ---------- phase 1: hid = relu(rel@W1+b1) -> bf16 LDS ----------
    {
        const float w10 = W1[ch];
        const float w11 = W1[CH + ch];
        const float bb  = b1[ch];
        for (int rr = g; rr < R; rr += 2) {
            float h = fmaf(rel_s[rr][0], w10, fmaf(rel_s[rr][1], w11, bb));
            hid_s[rr * HSTR + ch] = f2bf(fmaxf(h, 0.0f));
        }
        for (int t = tid; t < 15 * HSTR; t += 256) hid_s[R * HSTR + t] = 0;
    }
    __syncthreads();

    // ---------- window geometry ----------
    const int winbase = s * (R * CH) + (ii - 3) * CH + (jj - 3);
    const int m2v = winbase & 1;
    const int hw  = winbase >> 1;
    const int m3  = hw & 3;
    const int cw0 = (hw - m3) >> 2;               // u32x4 chunk base (batch plane)
    const u32x4* x2v = reinterpret_cast<const u32x4*>(x2);
    const unsigned short* x2s = reinterpret_cast<const unsigned short*>(x2);

    u32x4 v[4];
    auto ld = [&](int b) {
        const int cb = b * (XSTR >> 3) + cw0;
        const bool safe = (b > 0 || winbase >= 8) && (b < BS - 1 || winbase + 6280 <= XSTR);
        if (safe) {
            v[0] = x2v[cb + tid];
            v[1] = x2v[cb + tid + 256];
            v[2] = x2v[cb + tid + 512];
            if (tid < 17) v[3] = x2v[cb + tid + 768];
        } else {
            #pragma unroll
            for (int j = 0; j < 4; ++j) {
                if (j < 3 || tid < 17) {
                    int gc = cb + tid + 256 * j;
                    u32x4 o;
                    #pragma unroll
                    for (int kk = 0; kk < 4; ++kk) {
                        int e0 = 8 * gc + 2 * kk;
                        int a0 = e0;     a0 = a0 < 0 ? 0 : (a0 >= XTOT ? XTOT - 1 : a0);
                        int a1 = e0 + 1; a1 = a1 < 0 ? 0 : (a1 >= XTOT ? XTOT - 1 : a1);
                        o[kk] = (u32)x2s[a0] | ((u32)x2s[a1] << 16);  // masked (w=0)
                    }
                    v[j] = o;
                }
            }
        }
    };
    auto st = [&](u32* wb) {   // linear layout, 4x ds_write_b128, conflict-free
        *reinterpret_cast<u32x4*>(&wb[4 * tid])         = v[0];
        *reinterpret_cast<u32x4*>(&wb[4 * (tid + 256)]) = v[1];
        *reinterpret_cast<u32x4*>(&wb[4 * (tid + 512)]) = v[2];
        if (tid < 17)
            *reinterpret_cast<u32x4*>(&wb[4 * (tid + 768)]) = v[3];
    };

    ld(0);   // batch-0 loads in flight across the MFMA phase

    // ---------- phase 2: P columns [32w,32w+32), kk-outer (A-frags shared) ----------
    const int wv_ = tid >> 6;
    const int l   = tid & 63;
    const int lr  = l & 15;
    const int kg  = l >> 4;

    f32x4 acc[4][2];
    #pragma unroll
    for (int mt = 0; mt < 4; ++mt) { acc[mt][0] = (f32x4)0.0f; acc[mt][1] = (f32x4)0.0f; }

    #pragma unroll
    for (int kk = 0; kk < 4; ++kk) {
        short8 aF[4];
        #pragma unroll
        for (int mt = 0; mt < 4; ++mt)
            aF[mt] = *reinterpret_cast<const short8*>(
                &hid_s[(16 * mt + lr) * HSTR + kk * 32 + kg * 8]);
        #pragma unroll
        for (int np = 0; np < 2; ++np) {
            const int bcol = 32 * wv_ + 16 * np + lr;
            short8 bH = *reinterpret_cast<const short8*>(wsH + bcol * CH + kk * 32 + kg * 8);
            short8 bL = *reinterpret_cast<const short8*>(wsL + bcol * CH + kk * 32 + kg * 8);
            #pragma unroll
            for (int mt = 0; mt < 4; ++mt) {
                acc[mt][np] = __builtin_amdgcn_mfma_f32_16x16x32_bf16(aF[mt], bH, acc[mt][np], 0, 0, 0);
                acc[mt][np] = __builtin_amdgcn_mfma_f32_16x16x32_bf16(aF[mt], bL, acc[mt][np], 0, 0, 0);
            }
        }
    }

    // ---------- phase 3: in-reg softmax + interval-bitmask mask -> wpack ----------
    {
        float wv[4][4];
        #pragma unroll
        for (int np = 0; np < 2; ++np) {
            const int chh = 32 * wv_ + 16 * np + lr;

            float mx = -1e30f;
            #pragma unroll
            for (int mt = 0; mt < 4; ++mt)
                #pragma unroll
                for (int r = 0; r < 4; ++r) {
                    int rr = 16 * mt + 4 * kg + r;
                    if (rr < R) mx = fmaxf(mx, acc[mt][np][r]);
                }
            mx = fmaxf(mx, __shfl_xor(mx, 16));
            mx = fmaxf(mx, __shfl_xor(mx, 32));

            float sm = 0.0f;
            #pragma unroll
            for (int mt = 0; mt < 4; ++mt)
                #pragma unroll
                for (int r = 0; r < 4; ++r) {
                    int rr = 16 * mt + 4 * kg + r;
                    float e = (rr < R) ? __expf(acc[mt][np][r] - mx) : 0.0f;
                    wv[mt][r] = e;
                    sm += e;
                }
            sm += __shfl_xor(sm, 16);
            sm += __shfl_xor(sm, 32);
            const float inv = 1.0f / sm;

            // validity bitmask over rr in [0,49)
            const int base = s * (R * CH) + chh * R;
            const int e2_0 = base & 127;
            const int jb   = base >> 7;
            const int j2_0 = jb % HH;
            const int rw   = 128 - e2_0;
            int j2p = j2_0 + 1; if (j2p == HH) j2p = 0;
            const bool rok1 = (j2_0 >= 3 - ii) && (j2_0 < 59 - ii);
            const bool rok2 = (j2p  >= 3 - ii) && (j2p  < 59 - ii);
            const int c1 = (3 - jj) - e2_0;
            const int c2 = (131 - jj) - e2_0;
            const int lo2 = c2 < rw ? c2 : rw;
            const int hi2 = c2 < rw ? rw : c2;
            u64 colm = ~(bitrange(0, c1) | bitrange(lo2, hi2));
            u64 rowm = (rok1 ? bitrange(0, rw) : 0ull) | (rok2 ? bitrange(rw, 49) : 0ull);
            u64 vm = (colm & rowm) >> (kg << 2);
            const u32 vlo = (u32)vm, vhi = (u32)(vm >> 32);

            #pragma unroll
            for (int mt = 0; mt < 4; ++mt)
                #pragma unroll
                for (int r = 0; r < 4; ++r) {
                    int rr = 16 * mt + 4 * kg + r;
                    if (rr < R) {
                        const int bp = 16 * mt + r;
                        bool ok = (((bp < 32 ? vlo : vhi) >> (bp & 31)) & 1u) != 0;
                        wv[mt][r] = ok ? wv[mt][r] * inv : 0.0f;
                    }
                }

            #pragma unroll
            for (int mt = 0; mt < 4; ++mt)
                #pragma unroll
                for (int jp = 0; jp < 2; ++jp) {
                    int j = 8 * mt + 2 * kg + jp;
                    if (j <= 24) {
                        u32 pk = (u32)(unsigned short)f2bf(wv[mt][2 * jp])
                               | ((u32)(unsigned short)f2bf(wv[mt][2 * jp + 1]) << 16);
                        wpack[j * CH + chh] = pk;
                    }
                }
        }
    }
    __syncthreads();          // hid dead (win0 overlay ok), wpack visible

    // ---------- per-thread weights: parity-aligned PACKED pairs qp[14] ----------
    u32 qp[14];
    {
        const int j0 = g ? 13 : 0;
        const int nj = g ? 12 : 13;
        u32 wr[14];
        #pragma unroll
        for (int i = 0; i < 13; ++i) wr[i] = (i < nj) ? wpack[(j0 + i) * CH + ch] : 0u;
        wr[13] = 0u;
        const int kw0 = g ? 26 : 0;
        const int par = (m2v + 49 * ch + kw0) & 1;
        u32 prev = 0u;
        #pragma unroll
        for (int i = 0; i < 14; ++i) {
            qp[i] = par ? ((wr[i] << 16) | (prev >> 16)) : wr[i];
            prev = wr[i];
        }
    }
#ifndef POATT_DOT2
    float qlo[14], qhi[14];
    #pragma unroll
    for (int i = 0; i < 14; ++i) {
        qlo[i] = bf2f_u(qp[i] & 0xffffu);
        qhi[i] = bf2f_u(qp[i] >> 16);
    }
#endif
    const int d0 = m3 + ((m2v + 49 * ch + (g ? 26 : 0)) >> 1);

    st(win0);                 // batch 0 -> win0 (hid dead; wpack reads done above)
    ld(1);                    // batch-1 loads in flight
    __syncthreads();          // win0 visible; all wpack reads complete

    // ---------- batch loop: double-buffered, ONE barrier per batch ----------
    #pragma unroll
    for (int b = 0; b < BS; ++b) {
        const u32* wb = (b & 1) ? win1 : win0;

        float acc2 = 0.0f;
        #pragma unroll
        for (int dd = 0; dd < 14; ++dd) {
            u32 wd = wb[d0 + dd];                // base + imm offset
#ifdef POATT_DOT2
            acc2 = __builtin_amdgcn_fdot2_f32_bf16(
                __builtin_bit_cast(bf16x2, wd),
                __builtin_bit_cast(bf16x2, qp[dd]),
                acc2, false);
#else
            acc2 = fmaf(__uint_as_float(wd << 16),         qlo[dd], acc2);
            acc2 = fmaf(__uint_as_float(wd & 0xffff0000u), qhi[dd], acc2);
#endif
        }

        if (b + 1 < BS) st((b & 1) ? win0 : win1);   // stage next batch into OTHER buf
        if (b + 2 < BS) ld(b + 2);                   // issue loads 2 batches ahead

        if (g) part_s[b & 1][ch] = acc2;
        __syncthreads();                              // next buf + part_s visible
        if (!g) trb[((size_t)b * NPOS + pos) * CH + ch] = acc2 + part_s[b & 1][ch];
    }
}

// ---------- transpose (b,pos,ch) -> (b,ch,pos) ----------
__global__ __launch_bounds__(256) void poatt_tr(
    const float* __restrict__ ws, float* __restrict__ out)
{
    __shared__ float t[64 * 129];
    const int blk = blockIdx.x;
    const int b   = blk / 49;
    const int p0  = (blk % 49) * 64;
    const int tid = threadIdx.x;

    const int chR = tid & 127, pR = tid >> 7;
    #pragma unroll
    for (int r = 0; r < 32; ++r) {
        int pl = pR + 2 * r;
        t[pl * 129 + chR] = ws[((size_t)b * NPOS + p0 + pl) * CH + chR];
    }
    __syncthreads();
    const int pW = tid & 63, chW0 = tid >> 6;
    #pragma unroll
    for (int c = 0; c < 32; ++c) {
        int chl = chW0 + 4 * c;
        out[((size_t)b * CH + chl) * NPOS + p0 + pW] = t[pW * 129 + chl];
    }
}

// ================= fallback: monolithic kernel (round-4 proven) =================
template<bool WS_W2, bool USE_WS>
__global__ __launch_bounds__(256, 4) void poatt_mono(
    const float* __restrict__ x,
    const float* __restrict__ W1, const float* __restrict__ b1,
    const float* __restrict__ W2,
    const short* __restrict__ wsH, const short* __restrict__ wsL,
    float* __restrict__ dst)
{
    __shared__ float rel_s[R][2];
    __shared__ __align__(16) char smem[2 * 64 * HSTR * 2];
    short* hidH = (short*)smem;
    short* hidL = hidH + 64 * HSTR;
    float* Pbuf = (float*)smem;

    const int pos = blockIdx.x;
    const int tid = threadIdx.x;
    const int ch  = tid & (CH - 1);
    const int g   = tid >> 7;

    const int q  = pos >> 6;
    const int ii = q / KS;
    const int jj = q % KS;

    if (tid < 2 * R) {
        const int e  = (tid >= R) ? 1 : 0;
        const int rr = tid - e * R;
        int F  = (pos * 2 + e) * R + rr;
        int ep = F & 1;
        int t  = F >> 1;
        int jp = t % HH; t /= HH;
        int a  = t % HH; t /= HH;
        int jc = t % KS;
        int ic = t / KS;
        int row = jp + ic - 3;
        int col = ep + jc - 3;
        float v = 0.0f;
        if (row >= 0 && row < HH && (col == 0 || col == 1)) {
            int f    = a * (HH * 2) + row * 2 + col;
            int cidx = f / NPOS;
            int p    = f - cidx * NPOS;
            int u    = (cidx == 0) ? (p / HH) : (p % HH);
            v = -3.0f + 6.0f * (float)u * (1.0f / 55.0f);
        }
        const float c0 = -3.0f + 6.0f * (float)(pos / HH) * (1.0f / 55.0f);
        const float c1 = -3.0f + 6.0f * (float)(pos % HH) * (1.0f / 55.0f);
        rel_s[rr][e] = v - ((e == 0) ? c0 : c1);
    }
    __syncthreads();

    {
        const float w10 = W1[ch];
        const float w11 = W1[CH + ch];
        const float bb  = b1[ch];
        for (int rr = g; rr < R; rr += 2) {
            float h = fmaf(rel_s[rr][0], w10, fmaf(rel_s[rr][1], w11, bb));
            h = fmaxf(h, 0.0f);
            short hi = f2bf(h);
            hidH[rr * HSTR + ch] = hi;
            hidL[rr * HSTR + ch] = f2bf(h - bf2f(hi));
        }
        for (int t = tid; t < 15 * HSTR; t += 256) {
            hidH[R * HSTR + t] = 0;
            hidL[R * HSTR + t] = 0;
        }
    }
    __syncthreads();

    {
        const int w  = tid >> 6;
        const int l  = tid & 63;
        const int lr = l & 15;
        const int kg = l >> 4;

        short8 aH[4], aL[4];
        const int abase = (16 * w + lr) * HSTR + kg * 8;
        #pragma unroll
        for (int kk = 0; kk < 4; ++kk) {
            aH[kk] = *reinterpret_cast<const short8*>(&hidH[abase + kk * 32]);
            aL[kk] = *reinterpret_cast<const short8*>(&hidL[abase + kk * 32]);
        }

        f32x4 acc[8];
        #pragma unroll
        for (int n = 0; n < 8; ++n) acc[n] = (f32x4)0.0f;

        #pragma unroll
        for (int n = 0; n < 8; ++n) {
            const int bcol = 16 * n + lr;
            #pragma unroll
            for (int kk = 0; kk < 4; ++kk) {
                short8 bH, bL;
                if (WS_W2) {
                    bH = *reinterpret_cast<const short8*>(wsH + bcol * CH + kk * 32 + kg * 8);
                    bL = *reinterpret_cast<const short8*>(wsL + bcol * CH + kk * 32 + kg * 8);
                } else {
                    #pragma unroll
                    for (int j = 0; j < 8; ++j) {
                        float ww = ((const float*)W2)[(kk * 32 + kg * 8 + j) * CH + bcol];
                        short hi = f2bf(ww);
                        bH[j] = hi;
                        bL[j] = f2bf(ww - bf2f(hi));
                    }
                }
                acc[n] = __builtin_amdgcn_mfma_f32_16x16x32_bf16(aL[kk], bH, acc[n], 0, 0, 0);
                acc[n] = __builtin_amdgcn_mfma_f32_16x16x32_bf16(aH[kk], bL, acc[n], 0, 0, 0);
                acc[n] = __builtin_amdgcn_mfma_f32_16x16x32_bf16(aH[kk], bH, acc[n], 0, 0, 0);
            }
        }
        __syncthreads();

        #pragma unroll
        for (int n = 0; n < 8; ++n) {
            #pragma unroll
            for (int r = 0; r < 4; ++r) {
                int rr = 16 * w + kg * 4 + r;
                if (rr < R) Pbuf[rr * PSTR + 16 * n + lr] = acc[n][r];
            }
        }
    }
    __syncthreads();

    if (tid < CH) {
        float p[R];
        #pragma unroll
        for (int rr = 0; rr < R; ++rr) p[rr] = Pbuf[rr * PSTR + tid];
        float mx = p[0];
        #pragma unroll
        for (int rr = 1; rr < R; ++rr) mx = fmaxf(mx, p[rr]);
        float s = 0.0f;
        #pragma unroll
        for (int rr = 0; rr < R; ++rr) { p[rr] = __expf(p[rr] - mx); s += p[rr]; }
        const float inv = 1.0f / s;
        const int wb0 = (pos & 63) * (R * CH);
        #pragma unroll
        for (int rr = 0; rr < R; ++rr) {
            int rem = wb0 + tid * R + rr;
            int e2  = rem & (CH - 1);
            int j2  = (rem >> 7) % HH;
            int row = j2 + ii - 3;
            int col = e2 + jj - 3;
            bool valid = (row >= 0) && (row < HH) && (col >= 0) && (col < CH);
            Pbuf[rr * PSTR + tid] = valid ? p[rr] * inv : 0.0f;
        }
    }
    __syncthreads();

    float p[R];
    #pragma unroll
    for (int rr = 0; rr < R; ++rr) p[rr] = Pbuf[rr * PSTR + ch];

    const int winbase = (pos & 63) * (R * CH) + (ii - 3) * CH + (jj - 3);
    const int base_t  = winbase + ch * R;

    #pragma unroll
    for (int bi = 0; bi < 4; ++bi) {
        const int b  = g * 4 + bi;
        const int ab = b * XSTR + base_t;
        const bool safe = (b > 0 || winbase >= 0) && (b < BS - 1 || winbase + R * CH <= XSTR);
        float acc = 0.0f;
        if (safe) {
            #pragma unroll
            for (int rr = 0; rr < R; ++rr) acc = fmaf(p[rr], x[ab + rr], acc);
        } else {
            #pragma unroll
            for (int rr = 0; rr < R; ++rr) {
                int a2 = ab + rr;
                a2 = a2 < 0 ? 0 : (a2 >= XTOT ? XTOT - 1 : a2);
                acc = fmaf(p[rr], x[a2], acc);
            }
        }
        if (USE_WS) dst[((size_t)b * NPOS + pos) * CH + ch] = acc;
        else        dst[((size_t)b * CH + ch) * NPOS + pos] = acc;
    }
}

extern "C" void kernel_launch(void* const* d_in, const int* in_sizes, int n_in,
                              void* d_out, int out_size, void* d_ws, size_t ws_size,
                              hipStream_t stream) {
    (void)in_sizes; (void)n_in; (void)out_size;
    const float* x  = (const float*)d_in[0];
    const float* W1 = (const float*)d_in[1];
    const float* b1 = (const float*)d_in[2];
    const float* W2 = (const float*)d_in[3];
    float* out = (float*)d_out;

    // ws layout: [W2T hi/lo 64KB][x2 bf16 6.125MB][trb 12.25MB]
    const size_t W2T_BYTES = 2u * CH * CH * sizeof(short);            //    65536
    const size_t X2_BYTES  = (size_t)XTOT * 2;                        //  6422528
    const size_t TRB_BYTES = (size_t)BS * NPOS * CH * sizeof(float);  // 12845056
    const size_t FULL = W2T_BYTES + X2_BYTES + TRB_BYTES;             // 19333120

    short* wsH = (short*)d_ws;
    short* wsL = wsH + CH * CH;

    if (ws_size >= FULL) {
        u32*   x2  = (u32*)((char*)d_ws + W2T_BYTES);
        float* trb = (float*)((char*)d_ws + W2T_BYTES + X2_BYTES);

        poatt_pc<<<dim3(XTOT / (256 * 8)), dim3(256), 0, stream>>>(x, W2, x2, wsH, wsL);
        poatt_fused<<<dim3(NPOS), dim3(256), 0, stream>>>(x2, W1, b1, wsH, wsL, trb);
        poatt_tr<<<dim3(BS * 49), dim3(256), 0, stream>>>(trb, out);
    } else if (ws_size >= W2T_BYTES + TRB_BYTES) {
        float* trb = (float*)((char*)d_ws + W2T_BYTES);
        poatt_prep<<<dim3(64), dim3(256), 0, stream>>>(W2, wsH, wsL);
        poatt_mono<true, true><<<dim3(NPOS), dim3(256), 0, stream>>>(
            x, W1, b1, W2, wsH, wsL, trb);
        poatt_tr<<<dim3(BS * 49), dim3(256), 0, stream>>>(trb, out);
    } else if (ws_size >= W2T_BYTES) {
        poatt_prep<<<dim3(64), dim3(256), 0, stream>>>(W2, wsH, wsL);
        poatt_mono<true, false><<<dim3(NPOS), dim3(256), 0, stream>>>(
            x, W1, b1, W2, wsH, wsL, out);
    } else {
        poatt_mono<false, false><<<dim3(NPOS), dim3(256), 0, stream>>>(
            x, W1, b1, W2, nullptr, nullptr, out);
    }
}

// Round 16
// 69.070 us; speedup vs baseline: 1.2614x; 1.0009x over previous
//
#include <hip/hip_runtime.h>

#define CH   128
#define KS   7
#define R    49
#define HH   56
#define NPOS 3136
#define BS   8
#define XSTR 401408
#define XTOT (BS*XSTR)

typedef short short8 __attribute__((ext_vector_type(8)));
typedef float f32x4  __attribute__((ext_vector_type(4)));
typedef unsigned int u32;
typedef unsigned long long u64;
typedef u32 u32x4 __attribute__((ext_vector_type(4)));
typedef __bf16 bf16x2 __attribute__((ext_vector_type(2)));

#if defined(__has_builtin)
#if __has_builtin(__builtin_amdgcn_fdot2_f32_bf16)
#define POATT_DOT2 1
#endif
#endif

__device__ __forceinline__ short f2bf(float f) {            // RNE fp32->bf16
    unsigned u = __float_as_uint(f);
    u += 0x7fffu + ((u >> 16) & 1u);
    return (short)(u >> 16);
}
__device__ __forceinline__ float bf2f(short s) {
    return __uint_as_float(((unsigned)(unsigned short)s) << 16);
}
__device__ __forceinline__ float bf2f_u(u32 lo16) {
    return __uint_as_float(lo16 << 16);
}
__device__ __forceinline__ u64 bitrange(int a, int b) {     // bits [a,b) clamped to [0,49]
    a = a < 0 ? 0 : (a > 49 ? 49 : a);
    b = b < 0 ? 0 : (b > 49 ? 49 : b);
    if (b <= a) return 0ull;
    return (1ull << b) - (1ull << a);
}

#define HSTR 136            // hid LDS row stride (bf16 elems)
#define PSTR 132            // P LDS row stride (fp32) - mono fallback only
#define NWIN 3140           // win dwords (785 u32x4 chunks)

// ---------- prep (fallback path only) ----------
__global__ __launch_bounds__(256) void poatt_prep(
    const float* __restrict__ W2, short* __restrict__ wsH, short* __restrict__ wsL)
{
    int t = blockIdx.x * 256 + threadIdx.x;
    int k = t >> 7, ch = t & 127;
    float w = W2[k * CH + ch];
    short hi = f2bf(w);
    wsH[ch * CH + k] = hi;
    wsL[ch * CH + k] = f2bf(w - bf2f(hi));
}

// ---------- combined: cvt x->bf16 pairs + W2 prep (first 64 blocks) ----------
__global__ __launch_bounds__(256) void poatt_pc(
    const float* __restrict__ x, const float* __restrict__ W2,
    u32* __restrict__ x2, short* __restrict__ wsH, short* __restrict__ wsL)
{
    int t = blockIdx.x * 256 + threadIdx.x;      // grid 1568
    const float4* xv = reinterpret_cast<const float4*>(x);
    float4 a = xv[2 * t], b = xv[2 * t + 1];
    u32x4 o;
    o[0] = (u32)(unsigned short)f2bf(a.x) | ((u32)(unsigned short)f2bf(a.y) << 16);
    o[1] = (u32)(unsigned short)f2bf(a.z) | ((u32)(unsigned short)f2bf(a.w) << 16);
    o[2] = (u32)(unsigned short)f2bf(b.x) | ((u32)(unsigned short)f2bf(b.y) << 16);
    o[3] = (u32)(unsigned short)f2bf(b.z) | ((u32)(unsigned short)f2bf(b.w) << 16);
    reinterpret_cast<u32x4*>(x2)[t] = o;

    if (t < CH * CH) {
        int k = t >> 7, ch = t & 127;
        float w = W2[k * CH + ch];
        short hi = f2bf(w);
        wsH[ch * CH + k] = hi;
        wsL[ch * CH + k] = f2bf(w - bf2f(hi));
    }
}

// ---------- fused: weights (MFMA + in-reg softmax) + 8-batch dbuf apply ----------
__global__ __launch_bounds__(256, 4) void poatt_fused(
    const u32* __restrict__ x2,
    const float* __restrict__ W1, const float* __restrict__ b1,
    const short* __restrict__ wsH, const short* __restrict__ wsL,
    float* __restrict__ trb)         // (b,pos,ch)
{
    __shared__ float rel_s[R][2];
    __shared__ float part_s[2][CH];
    __shared__ u32 wpack[25 * CH];                    // 12800 B: weights, then win1
    __shared__ __align__(16) char smem[64 * HSTR * 2];// 17408 B: hid, then win0
    short* hid_s = (short*)smem;
    u32*   win0  = (u32*)smem;                        // overlays hid
    u32*   win1  = wpack;                             // overlays wpack

    const int pos = blockIdx.x;                       // natural: XCD = s mod 8
    const int tid = threadIdx.x;
    const int ch  = tid & (CH - 1);
    const int g   = tid >> 7;

    const int q  = pos >> 6;
    const int s  = pos & 63;
    const int ii = q / KS;
    const int jj = q % KS;

    // ---------- phase 0: rel ----------
    if (tid < 2 * R) {
        const int e  = (tid >= R) ? 1 : 0;
        const int rr = tid - e * R;
        int F  = (pos * 2 + e) * R + rr;
        int ep = F & 1;
        int t  = F >> 1;
        int jp = t % HH; t /= HH;
        int a  = t % HH; t /= HH;
        int jc = t % KS;
        int ic = t / KS;
        int row = jp + ic - 3;
        int col = ep + jc - 3;
        float v = 0.0f;
        if (row >= 0 && row < HH && (col == 0 || col == 1)) {
            int f    = a * (HH * 2) + row * 2 + col;
            int cidx = f / NPOS;
            int p    = f - cidx * NPOS;
            int u    = (cidx == 0) ? (p / HH) : (p % HH);
            v = -3.0f + 6.0f * (float)u * (1.0f / 55.0f);
        }
        const float c0 = -3.0f + 6.0f * (float)(pos / HH) * (1.0f / 55.0f);
        const float c1 = -3.0f + 6.0f * (float)(pos % HH) * (1.0f / 55.0f);
        rel_s[rr][e] = v - ((e == 0) ? c0 : c1);
    }
    __syncthreads();

    // ---------- phase 1: hid = relu(rel@W1+b1) -> bf16 LDS ----------
    {
        const float w10 = W1[ch];
        const float w11 = W1[CH + ch];
        const float bb  = b1[ch];
        for (int rr = g; rr < R; rr += 2) {
            float h = fmaf(rel_s[rr][0], w10, fmaf(rel_s[rr][1], w11, bb));
            hid_s[rr * HSTR + ch] = f2bf(fmaxf(h, 0.0f));
        }
        for (int t = tid; t < 15 * HSTR; t += 256) hid_s[R * HSTR + t] = 0;
    }
    __syncthreads();

    // ---------- window geometry ----------
    const int winbase = s * (R * CH) + (ii - 3) * CH + (jj - 3);
    const int m2v = winbase & 1;
    const int hw  = winbase >> 1;
    const int m3  = hw & 3;
    const int cw0 = (hw - m3) >> 2;               // u32x4 chunk base (batch plane)
    const u32x4* x2v = reinterpret_cast<const u32x4*>(x2);
    const unsigned short* x2s = reinterpret_cast<const unsigned short*>(x2);

    u32x4 v[4];
    auto ld = [&](int b) {
        const int cb = b * (XSTR >> 3) + cw0;
        const bool safe = (b > 0 || winbase >= 8) && (b < BS - 1 || winbase + 6280 <= XSTR);
        if (safe) {
            v[0] = x2v[cb + tid];
            v[1] = x2v[cb + tid + 256];
            v[2] = x2v[cb + tid + 512];
            if (tid < 17) v[3] = x2v[cb + tid + 768];
        } else {
            #pragma unroll
            for (int j = 0; j < 4; ++j) {
                if (j < 3 || tid < 17) {
                    int gc = cb + tid + 256 * j;
                    u32x4 o;
                    #pragma unroll
                    for (int kk = 0; kk < 4; ++kk) {
                        int e0 = 8 * gc + 2 * kk;
                        int a0 = e0;     a0 = a0 < 0 ? 0 : (a0 >= XTOT ? XTOT - 1 : a0);
                        int a1 = e0 + 1; a1 = a1 < 0 ? 0 : (a1 >= XTOT ? XTOT - 1 : a1);
                        o[kk] = (u32)x2s[a0] | ((u32)x2s[a1] << 16);  // masked (w=0)
                    }
                    v[j] = o;
                }
            }
        }
    };
    auto st = [&](u32* wb) {   // linear layout, 4x ds_write_b128, conflict-free
        *reinterpret_cast<u32x4*>(&wb[4 * tid])         = v[0];
        *reinterpret_cast<u32x4*>(&wb[4 * (tid + 256)]) = v[1];
        *reinterpret_cast<u32x4*>(&wb[4 * (tid + 512)]) = v[2];
        if (tid < 17)
            *reinterpret_cast<u32x4*>(&wb[4 * (tid + 768)]) = v[3];
    };

    ld(0);   // batch-0 loads in flight across the MFMA phase

    // ---------- phase 2: P columns [32w,32w+32), kk-outer (A-frags shared) ----------
    const int wv_ = tid >> 6;
    const int l   = tid & 63;
    const int lr  = l & 15;
    const int kg  = l >> 4;

    f32x4 acc[4][2];
    #pragma unroll
    for (int mt = 0; mt < 4; ++mt) { acc[mt][0] = (f32x4)0.0f; acc[mt][1] = (f32x4)0.0f; }

    #pragma unroll
    for (int kk = 0; kk < 4; ++kk) {
        short8 aF[4];
        #pragma unroll
        for (int mt = 0; mt < 4; ++mt)
            aF[mt] = *reinterpret_cast<const short8*>(
                &hid_s[(16 * mt + lr) * HSTR + kk * 32 + kg * 8]);
        #pragma unroll
        for (int np = 0; np < 2; ++np) {
            const int bcol = 32 * wv_ + 16 * np + lr;
            short8 bH = *reinterpret_cast<const short8*>(wsH + bcol * CH + kk * 32 + kg * 8);
            short8 bL = *reinterpret_cast<const short8*>(wsL + bcol * CH + kk * 32 + kg * 8);
            #pragma unroll
            for (int mt = 0; mt < 4; ++mt) {
                acc[mt][np] = __builtin_amdgcn_mfma_f32_16x16x32_bf16(aF[mt], bH, acc[mt][np], 0, 0, 0);
                acc[mt][np] = __builtin_amdgcn_mfma_f32_16x16x32_bf16(aF[mt], bL, acc[mt][np], 0, 0, 0);
            }
        }
    }

    // ---------- phase 3: in-reg softmax + interval-bitmask mask -> wpack ----------
    {
        float wv[4][4];
        #pragma unroll
        for (int np = 0; np < 2; ++np) {
            const int chh = 32 * wv_ + 16 * np + lr;

            float mx = -1e30f;
            #pragma unroll
            for (int mt = 0; mt < 4; ++mt)
                #pragma unroll
                for (int r = 0; r < 4; ++r) {
                    int rr = 16 * mt + 4 * kg + r;
                    if (rr < R) mx = fmaxf(mx, acc[mt][np][r]);
                }
            mx = fmaxf(mx, __shfl_xor(mx, 16));
            mx = fmaxf(mx, __shfl_xor(mx, 32));

            float sm = 0.0f;
            #pragma unroll
            for (int mt = 0; mt < 4; ++mt)
                #pragma unroll
                for (int r = 0; r < 4; ++r) {
                    int rr = 16 * mt + 4 * kg + r;
                    float e = (rr < R) ? __expf(acc[mt][np][r] - mx) : 0.0f;
                    wv[mt][r] = e;
                    sm += e;
                }
            sm += __shfl_xor(sm, 16);
            sm += __shfl_xor(sm, 32);
            const float inv = 1.0f / sm;

            // validity bitmask over rr in [0,49)
            const int base = s * (R * CH) + chh * R;
            const int e2_0 = base & 127;
            const int jb   = base >> 7;
            const int j2_0 = jb % HH;
            const int rw   = 128 - e2_0;
            int j2p = j2_0 + 1; if (j2p == HH) j2p = 0;
            const bool rok1 = (j2_0 >= 3 - ii) && (j2_0 < 59 - ii);
            const bool rok2 = (j2p  >= 3 - ii) && (j2p  < 59 - ii);
            const int c1 = (3 - jj) - e2_0;
            const int c2 = (131 - jj) - e2_0;
            const int lo2 = c2 < rw ? c2 : rw;
            const int hi2 = c2 < rw ? rw : c2;
            u64 colm = ~(bitrange(0, c1) | bitrange(lo2, hi2));
            u64 rowm = (rok1 ? bitrange(0, rw) : 0ull) | (rok2 ? bitrange(rw, 49) : 0ull);
            u64 vm = (colm & rowm) >> (kg << 2);
            const u32 vlo = (u32)vm, vhi = (u32)(vm >> 32);

            #pragma unroll
            for (int mt = 0; mt < 4; ++mt)
                #pragma unroll
                for (int r = 0; r < 4; ++r) {
                    int rr = 16 * mt + 4 * kg + r;
                    if (rr < R) {
                        const int bp = 16 * mt + r;
                        bool ok = (((bp < 32 ? vlo : vhi) >> (bp & 31)) & 1u) != 0;
                        wv[mt][r] = ok ? wv[mt][r] * inv : 0.0f;
                    }
                }

            #pragma unroll
            for (int mt = 0; mt < 4; ++mt)
                #pragma unroll
                for (int jp = 0; jp < 2; ++jp) {
                    int j = 8 * mt + 2 * kg + jp;
                    if (j <= 24) {
                        u32 pk = (u32)(unsigned short)f2bf(wv[mt][2 * jp])
                               | ((u32)(unsigned short)f2bf(wv[mt][2 * jp + 1]) << 16);
                        wpack[j * CH + chh] = pk;
                    }
                }
        }
    }
    __syncthreads();          // hid dead (win0 overlay ok), wpack visible

    // ---------- per-thread weights: parity-aligned PACKED pairs qp[14] ----------
    u32 qp[14];
    {
        const int j0 = g ? 13 : 0;
        const int nj = g ? 12 : 13;
        u32 wr[14];
        #pragma unroll
        for (int i = 0; i < 13; ++i) wr[i] = (i < nj) ? wpack[(j0 + i) * CH + ch] : 0u;
        wr[13] = 0u;
        const int kw0 = g ? 26 : 0;
        const int par = (m2v + 49 * ch + kw0) & 1;
        u32 prev = 0u;
        #pragma unroll
        for (int i = 0; i < 14; ++i) {
            qp[i] = par ? ((wr[i] << 16) | (prev >> 16)) : wr[i];
            prev = wr[i];
        }
    }
#ifndef POATT_DOT2
    float qlo[14], qhi[14];
    #pragma unroll
    for (int i = 0; i < 14; ++i) {
        qlo[i] = bf2f_u(qp[i] & 0xffffu);
        qhi[i] = bf2f_u(qp[i] >> 16);
    }
#endif
    const int d0 = m3 + ((m2v + 49 * ch + (g ? 26 : 0)) >> 1);

    st(win0);                 // batch 0 -> win0 (hid dead; wpack reads done above)
    ld(1);                    // batch-1 loads in flight
    __syncthreads();          // win0 visible; all wpack reads complete

    // ---------- batch loop: double-buffered, ONE barrier per batch ----------
    #pragma unroll
    for (int b = 0; b < BS; ++b) {
        const u32* wb = (b & 1) ? win1 : win0;

        float acc2 = 0.0f;
        #pragma unroll
        for (int dd = 0; dd < 14; ++dd) {
            u32 wd = wb[d0 + dd];                // base + imm offset
#ifdef POATT_DOT2
            acc2 = __builtin_amdgcn_fdot2_f32_bf16(
                __builtin_bit_cast(bf16x2, wd),
                __builtin_bit_cast(bf16x2, qp[dd]),
                acc2, false);
#else
            acc2 = fmaf(__uint_as_float(wd << 16),         qlo[dd], acc2);
            acc2 = fmaf(__uint_as_float(wd & 0xffff0000u), qhi[dd], acc2);
#endif
        }

        if (b + 1 < BS) st((b & 1) ? win0 : win1);   // stage next batch into OTHER buf
        if (b + 2 < BS) ld(b + 2);                   // issue loads 2 batches ahead

        if (g) part_s[b & 1][ch] = acc2;
        __syncthreads();                              // next buf + part_s visible
        if (!g) trb[((size_t)b * NPOS + pos) * CH + ch] = acc2 + part_s[b & 1][ch];
    }
}

// ---------- transpose (b,pos,ch) -> (b,ch,pos) ----------
__global__ __launch_bounds__(256) void poatt_tr(
    const float* __restrict__ ws, float* __restrict__ out)
{
    __shared__ float t[64 * 129];
    const int blk = blockIdx.x;
    const int b   = blk / 49;
    const int p0  = (blk % 49) * 64;
    const int tid = threadIdx.x;

    const int chR = tid & 127, pR = tid >> 7;
    #pragma unroll
    for (int r = 0; r < 32; ++r) {
        int pl = pR + 2 * r;
        t[pl * 129 + chR] = ws[((size_t)b * NPOS + p0 + pl) * CH + chR];
    }
    __syncthreads();
    const int pW = tid & 63, chW0 = tid >> 6;
    #pragma unroll
    for (int c = 0; c < 32; ++c) {
        int chl = chW0 + 4 * c;
        out[((size_t)b * CH + chl) * NPOS + p0 + pW] = t[pW * 129 + chl];
    }
}

// ================= fallback: monolithic kernel (round-4 proven) =================
template<bool WS_W2, bool USE_WS>
__global__ __launch_bounds__(256, 4) void poatt_mono(
    const float* __restrict__ x,
    const float* __restrict__ W1, const float* __restrict__ b1,
    const float* __restrict__ W2,
    const short* __restrict__ wsH, const short* __restrict__ wsL,
    float* __restrict__ dst)
{
    __shared__ float rel_s[R][2];
    __shared__ __align__(16) char smem[2 * 64 * HSTR * 2];
    short* hidH = (short*)smem;
    short* hidL = hidH + 64 * HSTR;
    float* Pbuf = (float*)smem;

    const int pos = blockIdx.x;
    const int tid = threadIdx.x;
    const int ch  = tid & (CH - 1);
    const int g   = tid >> 7;

    const int q  = pos >> 6;
    const int ii = q / KS;
    const int jj = q % KS;

    if (tid < 2 * R) {
        const int e  = (tid >= R) ? 1 : 0;
        const int rr = tid - e * R;
        int F  = (pos * 2 + e) * R + rr;
        int ep = F & 1;
        int t  = F >> 1;
        int jp = t % HH; t /= HH;
        int a  = t % HH; t /= HH;
        int jc = t % KS;
        int ic = t / KS;
        int row = jp + ic - 3;
        int col = ep + jc - 3;
        float v = 0.0f;
        if (row >= 0 && row < HH && (col == 0 || col == 1)) {
            int f    = a * (HH * 2) + row * 2 + col;
            int cidx = f / NPOS;
            int p    = f - cidx * NPOS;
            int u    = (cidx == 0) ? (p / HH) : (p % HH);
            v = -3.0f + 6.0f * (float)u * (1.0f / 55.0f);
        }
        const float c0 = -3.0f + 6.0f * (float)(pos / HH) * (1.0f / 55.0f);
        const float c1 = -3.0f + 6.0f * (float)(pos % HH) * (1.0f / 55.0f);
        rel_s[rr][e] = v - ((e == 0) ? c0 : c1);
    }
    __syncthreads();

    {
        const float w10 = W1[ch];
        const float w11 = W1[CH + ch];
        const float bb  = b1[ch];
        for (int rr = g; rr < R; rr += 2) {
            float h = fmaf(rel_s[rr][0], w10, fmaf(rel_s[rr][1], w11, bb));
            h = fmaxf(h, 0.0f);
            short hi = f2bf(h);
            hidH[rr * HSTR + ch] = hi;
            hidL[rr * HSTR + ch] = f2bf(h - bf2f(hi));
        }
        for (int t = tid; t < 15 * HSTR; t += 256) {
            hidH[R * HSTR + t] = 0;
            hidL[R * HSTR + t] = 0;
        }
    }
    __syncthreads();

    {
        const int w  = tid >> 6;
        const int l  = tid & 63;
        const int lr = l & 15;
        const int kg = l >> 4;

        short8 aH[4], aL[4];
        const int abase = (16 * w + lr) * HSTR + kg * 8;
        #pragma unroll
        for (int kk = 0; kk < 4; ++kk) {
            aH[kk] = *reinterpret_cast<const short8*>(&hidH[abase + kk * 32]);
            aL[kk] = *reinterpret_cast<const short8*>(&hidL[abase + kk * 32]);
        }

        f32x4 acc[8];
        #pragma unroll
        for (int n = 0; n < 8; ++n) acc[n] = (f32x4)0.0f;

        #pragma unroll
        for (int n = 0; n < 8; ++n) {
            const int bcol = 16 * n + lr;
            #pragma unroll
            for (int kk = 0; kk < 4; ++kk) {
                short8 bH, bL;
                if (WS_W2) {
                    bH = *reinterpret_cast<const short8*>(wsH + bcol * CH + kk * 32 + kg * 8);
                    bL = *reinterpret_cast<const short8*>(wsL + bcol * CH + kk * 32 + kg * 8);
                } else {
                    #pragma unroll
                    for (int j = 0; j < 8; ++j) {
                        float ww = ((const float*)W2)[(kk * 32 + kg * 8 + j) * CH + bcol];
                        short hi = f2bf(ww);
                        bH[j] = hi;
                        bL[j] = f2bf(ww - bf2f(hi));
                    }
                }
                acc[n] = __builtin_amdgcn_mfma_f32_16x16x32_bf16(aL[kk], bH, acc[n], 0, 0, 0);
                acc[n] = __builtin_amdgcn_mfma_f32_16x16x32_bf16(aH[kk], bL, acc[n], 0, 0, 0);
                acc[n] = __builtin_amdgcn_mfma_f32_16x16x32_bf16(aH[kk], bH, acc[n], 0, 0, 0);
            }
        }
        __syncthreads();

        #pragma unroll
        for (int n = 0; n < 8; ++n) {
            #pragma unroll
            for (int r = 0; r < 4; ++r) {
                int rr = 16 * w + kg * 4 + r;
                if (rr < R) Pbuf[rr * PSTR + 16 * n + lr] = acc[n][r];
            }
        }
    }
    __syncthreads();

    if (tid < CH) {
        float p[R];
        #pragma unroll
        for (int rr = 0; rr < R; ++rr) p[rr] = Pbuf[rr * PSTR + tid];
        float mx = p[0];
        #pragma unroll
        for (int rr = 1; rr < R; ++rr) mx = fmaxf(mx, p[rr]);
        float s = 0.0f;
        #pragma unroll
        for (int rr = 0; rr < R; ++rr) { p[rr] = __expf(p[rr] - mx); s += p[rr]; }
        const float inv = 1.0f / s;
        const int wb0 = (pos & 63) * (R * CH);
        #pragma unroll
        for (int rr = 0; rr < R; ++rr) {
            int rem = wb0 + tid * R + rr;
            int e2  = rem & (CH - 1);
            int j2  = (rem >> 7) % HH;
            int row = j2 + ii - 3;
            int col = e2 + jj - 3;
            bool valid = (row >= 0) && (row < HH) && (col >= 0) && (col < CH);
            Pbuf[rr * PSTR + tid] = valid ? p[rr] * inv : 0.0f;
        }
    }
    __syncthreads();

    float p[R];
    #pragma unroll
    for (int rr = 0; rr < R; ++rr) p[rr] = Pbuf[rr * PSTR + ch];

    const int winbase = (pos & 63) * (R * CH) + (ii - 3) * CH + (jj - 3);
    const int base_t  = winbase + ch * R;

    #pragma unroll
    for (int bi = 0; bi < 4; ++bi) {
        const int b  = g * 4 + bi;
        const int ab = b * XSTR + base_t;
        const bool safe = (b > 0 || winbase >= 0) && (b < BS - 1 || winbase + R * CH <= XSTR);
        float acc = 0.0f;
        if (safe) {
            #pragma unroll
            for (int rr = 0; rr < R; ++rr) acc = fmaf(p[rr], x[ab + rr], acc);
        } else {
            #pragma unroll
            for (int rr = 0; rr < R; ++rr) {
                int a2 = ab + rr;
                a2 = a2 < 0 ? 0 : (a2 >= XTOT ? XTOT - 1 : a2);
                acc = fmaf(p[rr], x[a2], acc);
            }
        }
        if (USE_WS) dst[((size_t)b * NPOS + pos) * CH + ch] = acc;
        else        dst[((size_t)b * CH + ch) * NPOS + pos] = acc;
    }
}

extern "C" void kernel_launch(void* const* d_in, const int* in_sizes, int n_in,
                              void* d_out, int out_size, void* d_ws, size_t ws_size,
                              hipStream_t stream) {
    (void)in_sizes; (void)n_in; (void)out_size;
    const float* x  = (const float*)d_in[0];
    const float* W1 = (const float*)d_in[1];
    const float* b1 = (const float*)d_in[2];
    const float* W2 = (const float*)d_in[3];
    float* out = (float*)d_out;

    // ws layout: [W2T hi/lo 64KB][x2 bf16 6.125MB][trb 12.25MB]
    const size_t W2T_BYTES = 2u * CH * CH * sizeof(short);            //    65536
    const size_t X2_BYTES  = (size_t)XTOT * 2;                        //  6422528
    const size_t TRB_BYTES = (size_t)BS * NPOS * CH * sizeof(float);  // 12845056
    const size_t FULL = W2T_BYTES + X2_BYTES + TRB_BYTES;             // 19333120

    short* wsH = (short*)d_ws;
    short* wsL = wsH + CH * CH;

    if (ws_size >= FULL) {
        u32*   x2  = (u32*)((char*)d_ws + W2T_BYTES);
        float* trb = (float*)((char*)d_ws + W2T_BYTES + X2_BYTES);

        poatt_pc<<<dim3(XTOT / (256 * 8)), dim3(256), 0, stream>>>(x, W2, x2, wsH, wsL);
        poatt_fused<<<dim3(NPOS), dim3(256), 0, stream>>>(x2, W1, b1, wsH, wsL, trb);
        poatt_tr<<<dim3(BS * 49), dim3(256), 0, stream>>>(trb, out);
    } else if (ws_size >= W2T_BYTES + TRB_BYTES) {
        float* trb = (float*)((char*)d_ws + W2T_BYTES);
        poatt_prep<<<dim3(64), dim3(256), 0, stream>>>(W2, wsH, wsL);
        poatt_mono<true, true><<<dim3(NPOS), dim3(256), 0, stream>>>(
            x, W1, b1, W2, wsH, wsL, trb);
        poatt_tr<<<dim3(BS * 49), dim3(256), 0, stream>>>(trb, out);
    } else if (ws_size >= W2T_BYTES) {
        poatt_prep<<<dim3(64), dim3(256), 0, stream>>>(W2, wsH, wsL);
        poatt_mono<true, false><<<dim3(NPOS), dim3(256), 0, stream>>>(
            x, W1, b1, W2, wsH, wsL, out);
    } else {
        poatt_mono<false, false><<<dim3(NPOS), dim3(256), 0, stream>>>(
            x, W1, b1, W2, nullptr, nullptr, out);
    }
}